// Round 9
// baseline (263.010 us; speedup 1.0000x reference)
//
#include <hip/hip_runtime.h>

#define N 8192
#define C 64
#define S 16

static constexpr float BN_INV = 0.9999950000374997f; // 1/sqrt(1+1e-5)
static constexpr float LN_EPS = 1e-5f;

typedef _Float16 f16x8 __attribute__((ext_vector_type(8)));
typedef float f32x4 __attribute__((ext_vector_type(4)));

__device__ __forceinline__ void sort2(unsigned& x, unsigned& y)
{
    unsigned lo = min(x, y);
    unsigned hi = max(x, y);
    x = lo;
    y = hi;
}

// ---------------------------------------------------------------------------
// K1: FUSED knn + qkv. 544 blocks x 1024 thr. Blocks [0,512): exact 16-NN,
// 16 queries/block (halves idx4 staging traffic vs 8/block). Blocks
// [512,544): MFMA-f16 qkv, 256 rows/block.
// ---------------------------------------------------------------------------
__global__ __launch_bounds__(1024) void qkv_knn_kernel(
    const int4* __restrict__ idx4, int* __restrict__ knn_out,
    const float* __restrict__ feats,
    const float* __restrict__ Wq, const float* __restrict__ bq,
    const float* __restrict__ Wk, const float* __restrict__ bk,
    const float* __restrict__ Wv, const float* __restrict__ bv,
    float* __restrict__ xq, float* __restrict__ xk, float* __restrict__ xv)
{
    extern __shared__ char smem[];
    const int t = threadIdx.x;
    const int lane = t & 63;
    const int wv = t >> 6;
    if (blockIdx.x < 512) {
        unsigned* pk = (unsigned*)smem;
        const int q = blockIdx.x * 16 + wv;
#pragma unroll
        for (int i = 0; i < 8; i++) {
            int j = i * 1024 + t;
            int4 c = idx4[j];
            pk[j] = (unsigned)c.y | ((unsigned)c.z << 8) |
                    ((unsigned)c.w << 16);
        }
        const int4 qc = idx4[q];
        const int qx = qc.y, qy = qc.z, qz = qc.w;
        const unsigned qq = (unsigned)(qx * qx + qy * qy + qz * qz);
#if __has_builtin(__builtin_amdgcn_udot4)
        const unsigned qpk2 = (unsigned)(2 * qx) | ((unsigned)(2 * qy) << 8) |
                              ((unsigned)(2 * qz) << 16);
#endif
        unsigned a0 = 0xFFFFFFFFu, a1 = 0xFFFFFFFFu, a2 = 0xFFFFFFFFu,
                 a3 = 0xFFFFFFFFu;
        unsigned b0 = 0xFFFFFFFFu, b1 = 0xFFFFFFFFu, b2 = 0xFFFFFFFFu,
                 b3 = 0xFFFFFFFFu;
        __syncthreads();
#pragma unroll 4
        for (int i = 0; i < 64; ++i) {
            int jA = i * 64 + lane;
            int jB = (i + 64) * 64 + lane;
            unsigned pA = pk[jA];
            unsigned pB = pk[jB];
#if __has_builtin(__builtin_amdgcn_udot4)
            unsigned d2A = __builtin_amdgcn_udot4(pA, pA, qq, false) -
                           __builtin_amdgcn_udot4(pA, qpk2, 0u, false);
            unsigned d2B = __builtin_amdgcn_udot4(pB, pB, qq, false) -
                           __builtin_amdgcn_udot4(pB, qpk2, 0u, false);
#else
            int xa = (int)(pA & 255u), ya = (int)((pA >> 8) & 255u),
                za = (int)(pA >> 16);
            int xb = (int)(pB & 255u), yb = (int)((pB >> 8) & 255u),
                zb = (int)(pB >> 16);
            int dxa = xa - qx, dya = ya - qy, dza = za - qz;
            int dxb = xb - qx, dyb = yb - qy, dzb = zb - qz;
            unsigned d2A = (unsigned)(dxa * dxa + dya * dya + dza * dza);
            unsigned d2B = (unsigned)(dxb * dxb + dyb * dyb + dzb * dzb);
#endif
            unsigned keyA = (d2A << 13) + (unsigned)jA;
            unsigned keyB = (d2B << 13) + (unsigned)jB;
            a3 = min(a3, keyA);
            sort2(a2, a3); sort2(a1, a2); sort2(a0, a1);
            b3 = min(b3, keyB);
            sort2(b2, b3); sort2(b1, b2); sort2(b0, b1);
        }
        unsigned t0 = min(a0, b3), t1 = min(a1, b2), t2 = min(a2, b1),
                 t3 = min(a3, b0);
        sort2(t0, t2); sort2(t1, t3); sort2(t0, t1); sort2(t2, t3);
        sort2(t1, t2);
        const unsigned t3pre = t3;
        unsigned g16 = 0;
        for (int r = 0; r < 16; ++r) {
            unsigned m = t0;
            m = min(m, (unsigned)__shfl_xor((int)m, 1, 64));
            m = min(m, (unsigned)__shfl_xor((int)m, 2, 64));
            m = min(m, (unsigned)__shfl_xor((int)m, 4, 64));
            m = min(m, (unsigned)__shfl_xor((int)m, 8, 64));
            m = min(m, (unsigned)__shfl_xor((int)m, 16, 64));
            m = min(m, (unsigned)__shfl_xor((int)m, 32, 64));
            if (lane == r) knn_out[q * 16 + r] = (int)(m & 8191u);
            bool win = (t0 == m);
            t0 = win ? t1 : t0;
            t1 = win ? t2 : t1;
            t2 = win ? t3 : t2;
            t3 = win ? 0xFFFFFFFFu : t3;
            g16 = m;
        }
        unsigned long long bad = __ballot(t3pre < g16);
        if (bad) {
            unsigned c0 = 0xFFFFFFFFu, c1 = 0xFFFFFFFFu, c2 = 0xFFFFFFFFu,
                     c3 = 0xFFFFFFFFu, c4 = 0xFFFFFFFFu, c5 = 0xFFFFFFFFu,
                     c6 = 0xFFFFFFFFu, c7 = 0xFFFFFFFFu, c8 = 0xFFFFFFFFu,
                     c9 = 0xFFFFFFFFu, c10 = 0xFFFFFFFFu, c11 = 0xFFFFFFFFu,
                     c12 = 0xFFFFFFFFu, c13 = 0xFFFFFFFFu, c14 = 0xFFFFFFFFu,
                     c15 = 0xFFFFFFFFu;
            for (int i = 0; i < 128; ++i) {
                int j = i * 64 + lane;
                int4 cd = idx4[j];
                int dx = cd.y - qx, dy = cd.z - qy, dz = cd.w - qz;
                unsigned d2 = (unsigned)(dx * dx + dy * dy + dz * dz);
                unsigned key = (d2 << 13) + (unsigned)j;
                c15 = min(c15, key);
                sort2(c14, c15); sort2(c13, c14); sort2(c12, c13);
                sort2(c11, c12); sort2(c10, c11); sort2(c9, c10);
                sort2(c8, c9);   sort2(c7, c8);   sort2(c6, c7);
                sort2(c5, c6);   sort2(c4, c5);   sort2(c3, c4);
                sort2(c2, c3);   sort2(c1, c2);   sort2(c0, c1);
            }
            for (int r = 0; r < 16; ++r) {
                unsigned m = c0;
                m = min(m, (unsigned)__shfl_xor((int)m, 1, 64));
                m = min(m, (unsigned)__shfl_xor((int)m, 2, 64));
                m = min(m, (unsigned)__shfl_xor((int)m, 4, 64));
                m = min(m, (unsigned)__shfl_xor((int)m, 8, 64));
                m = min(m, (unsigned)__shfl_xor((int)m, 16, 64));
                m = min(m, (unsigned)__shfl_xor((int)m, 32, 64));
                if (lane == r) knn_out[q * 16 + r] = (int)(m & 8191u);
                bool win = (c0 == m);
                c0 = win ? c1 : c0;    c1 = win ? c2 : c1;
                c2 = win ? c3 : c2;    c3 = win ? c4 : c3;
                c4 = win ? c5 : c4;    c5 = win ? c6 : c5;
                c6 = win ? c7 : c6;    c7 = win ? c8 : c7;
                c8 = win ? c9 : c8;    c9 = win ? c10 : c9;
                c10 = win ? c11 : c10; c11 = win ? c12 : c11;
                c12 = win ? c13 : c12; c13 = win ? c14 : c13;
                c14 = win ? c15 : c14; c15 = win ? 0xFFFFFFFFu : c15;
            }
        }
    } else {
        _Float16* sBt = (_Float16*)smem;
        float* sbias = (float*)(smem + 192 * 72 * 2);
        const int col = lane & 15, g = lane >> 4;
        const int bid2 = blockIdx.x - 512;
        const int row0w = bid2 * 256 + wv * 16;
        if (t < 512) {
            const float* Ws[3] = {Wq, Wk, Wv};
#pragma unroll
            for (int m = 0; m < 3; m++) {
                int k = t >> 3, nb = (t & 7) * 8;
                const float4* src = (const float4*)(Ws[m] + k * 64 + nb);
                float4 w0 = src[0], w1 = src[1];
                _Float16* dst = &sBt[(m * 64 + nb) * 72 + k];
                dst[0 * 72] = (_Float16)w0.x; dst[1 * 72] = (_Float16)w0.y;
                dst[2 * 72] = (_Float16)w0.z; dst[3 * 72] = (_Float16)w0.w;
                dst[4 * 72] = (_Float16)w1.x; dst[5 * 72] = (_Float16)w1.y;
                dst[6 * 72] = (_Float16)w1.z; dst[7 * 72] = (_Float16)w1.w;
            }
            if (t < 64) sbias[t] = bq[t];
            else if (t < 128) sbias[t] = bk[t - 64];
            else if (t < 192) sbias[t] = bv[t - 128];
        }
        __syncthreads();
        f16x8 au[2];
#pragma unroll
        for (int kc = 0; kc < 2; kc++) {
            const float4* src = (const float4*)
                (feats + (row0w + col) * 64 + kc * 32 + g * 8);
            float4 v0 = src[0], v1 = src[1];
            au[kc][0] = (_Float16)v0.x; au[kc][1] = (_Float16)v0.y;
            au[kc][2] = (_Float16)v0.z; au[kc][3] = (_Float16)v0.w;
            au[kc][4] = (_Float16)v1.x; au[kc][5] = (_Float16)v1.y;
            au[kc][6] = (_Float16)v1.z; au[kc][7] = (_Float16)v1.w;
        }
        float* outs[3] = {xq, xk, xv};
#pragma unroll
        for (int f = 0; f < 12; f++) {
            f32x4 acc;
            float bias = sbias[f * 16 + col];
#pragma unroll
            for (int r = 0; r < 4; r++) acc[r] = bias;
#pragma unroll
            for (int kc = 0; kc < 2; kc++) {
                f16x8 bw = *(const f16x8*)
                    &sBt[(f * 16 + col) * 72 + kc * 32 + g * 8];
                acc = __builtin_amdgcn_mfma_f32_16x16x32_f16(au[kc], bw, acc,
                                                             0, 0, 0);
            }
            float* o = outs[f >> 2];
            int cg = (f & 3) * 16 + col;
#pragma unroll
            for (int r = 0; r < 4; r++)
                o[(row0w + g * 4 + r) * 64 + cg] = acc[r];
        }
    }
}

// ---------------------------------------------------------------------------
// K2: MFMA vector-attention, LOW-LDS version (~37KB -> 3 blocks/CU, 24
// waves/CU vs 16 in R7). One 18KB slab holds W1t (stride 72) during GEMM1,
// then is RESTAGED with W2t (stride 136) for GEMM2; o1 rides the barrier in
// 16 f16 VGPRs; GEMM2 done in two K-halves through the per-wave u-scratch.
// bw2 is dropped: a per-channel constant added to logits cancels in the
// softmax over s.
// ---------------------------------------------------------------------------
__global__ __launch_bounds__(512, 6) void attn_kernel(
    const int4* __restrict__ idx4, const int* __restrict__ knn,
    const float* __restrict__ xq, const float* __restrict__ xk,
    const float* __restrict__ xv,
    const float* __restrict__ Wp1, const float* __restrict__ pg,
    const float* __restrict__ pb, const float* __restrict__ Wp2,
    const float* __restrict__ bp2,
    const float* __restrict__ wg1, const float* __restrict__ wb1,
    const float* __restrict__ Ww1,
    const float* __restrict__ wg2, const float* __restrict__ wb2,
    const float* __restrict__ Ww2,
    float* __restrict__ attn)
{
    __shared__ _Float16 slabW[9216];   // W1t 128x72 OR W2t 64x136
    __shared__ _Float16 su[8][1152];   // per-wave 16x72 scratch (u / o1 half)
    __shared__ float sWp1[48], sPg[16], sPb[16];

    const int t = threadIdx.x;
    const int lane = t & 63;
    const int wv = t >> 6;
    const int col = lane & 15, g = lane >> 4;
    const int q = blockIdx.x * 8 + wv;

    // per-query gather chain first
    const int jA = knn[q * 16 + col];
    const int4 jC = *(const int4*)(knn + q * 16 + g * 4);
    const int jr[4] = {jC.x, jC.y, jC.z, jC.w};
    const int4 pc = idx4[jA];
    const int4 qc = idx4[q];
    float xqv[4], xkv[4][4], xvv[4][4];
#pragma unroll
    for (int f = 0; f < 4; f++) xqv[f] = xq[q * 64 + f * 16 + col];
#pragma unroll
    for (int r = 0; r < 4; r++)
#pragma unroll
        for (int f = 0; f < 4; f++) {
            xkv[r][f] = xk[jr[r] * 64 + f * 16 + col];
            xvv[r][f] = xv[jr[r] * 64 + f * 16 + col];
        }

    // stage W1t (stride 72)
    for (int e = t; e < 8192; e += 512) {
        int c = e >> 7, o = e & 127;
        slabW[o * 72 + c] = (_Float16)Ww1[e];
    }
    if (t < 48) sWp1[t] = Wp1[t];
    if (t < 16) { sPg[t] = pg[t] * BN_INV; sPb[t] = pb[t]; }

    float g1c[4], b1c[4], bp2c[4], g2c[8], b2c[8];
#pragma unroll
    for (int f = 0; f < 4; f++) {
        int c = f * 16 + col;
        g1c[f] = wg1[c] * BN_INV; b1c[f] = wb1[c];
        bp2c[f] = bp2[c];
    }
#pragma unroll
    for (int f = 0; f < 8; f++) {
        int o = f * 16 + col;
        g2c[f] = wg2[o] * BN_INV; b2c[f] = wb2[o];
    }
    f16x8 bP[4];
#pragma unroll
    for (int f = 0; f < 4; f++) {
#pragma unroll
        for (int j = 0; j < 8; j++) {
            int h = g * 8 + j;
            bP[f][j] = (g < 2) ? (_Float16)Wp2[h * 64 + f * 16 + col]
                               : (_Float16)0.f;
        }
    }
    __syncthreads();

    _Float16* su_w = su[wv];

    // ---- p_r ----
    const float px = (float)(pc.y - qc.y);
    const float py = (float)(pc.z - qc.z);
    const float pz = (float)(pc.w - qc.w);
    f16x8 aph;
#pragma unroll
    for (int j = 0; j < 8; j++) {
        int h = g * 8 + j;
        float v = 0.f;
        if (g < 2) {
            v = px * sWp1[h] + py * sWp1[16 + h] + pz * sWp1[32 + h];
            v = fmaxf(v * sPg[h] + sPb[h], 0.f);
        }
        aph[j] = (_Float16)v;
    }
    f32x4 pr[4];
#pragma unroll
    for (int f = 0; f < 4; f++) {
        f32x4 cini;
#pragma unroll
        for (int r = 0; r < 4; r++) cini[r] = bp2c[f];
        pr[f] = __builtin_amdgcn_mfma_f32_16x16x32_f16(aph, bP[f], cini,
                                                       0, 0, 0);
    }
    // ---- u -> su; v in regs ----
    f32x4 vvr[4];
#pragma unroll
    for (int r = 0; r < 4; r++) {
#pragma unroll
        for (int f = 0; f < 4; f++) {
            float w0 = xkv[r][f] - xqv[f] + pr[f][r];
            float uu = fmaxf(w0 * g1c[f] + b1c[f], 0.f);
            su_w[(g * 4 + r) * 72 + f * 16 + col] = (_Float16)uu;
            vvr[f][r] = xvv[r][f] + pr[f][r];
        }
    }
    // ---- GEMM1: all 16 MFMAs; o1 kept in f16 regs across the restage ----
    f16x8 au[2];
#pragma unroll
    for (int kc = 0; kc < 2; kc++)
        au[kc] = *(const f16x8*)&su_w[col * 72 + kc * 32 + g * 8];
    _Float16 o1v[8][4];
    {
        f32x4 acc1[8];
#pragma unroll
        for (int f = 0; f < 8; f++)
#pragma unroll
            for (int r = 0; r < 4; r++) acc1[f][r] = 0.f;
#pragma unroll
        for (int kc = 0; kc < 2; kc++) {
#pragma unroll
            for (int f = 0; f < 8; f++) {
                f16x8 bw = *(const f16x8*)
                    &slabW[(f * 16 + col) * 72 + kc * 32 + g * 8];
                acc1[f] = __builtin_amdgcn_mfma_f32_16x16x32_f16(
                    au[kc], bw, acc1[f], 0, 0, 0);
            }
        }
#pragma unroll
        for (int f = 0; f < 8; f++)
#pragma unroll
            for (int r = 0; r < 4; r++)
                o1v[f][r] =
                    (_Float16)fmaxf(acc1[f][r] * g2c[f] + b2c[f], 0.f);
    }
    __syncthreads(); // all waves done reading W1t
    // restage slab with W2t (stride 136)
    for (int e = t; e < 8192; e += 512) {
        int n = e >> 6, m = e & 63;
        slabW[m * 136 + n] = (_Float16)Ww2[e];
    }
    __syncthreads();
    // ---- GEMM2 in two K-halves through su (bw2 cancels in softmax) ----
    f32x4 accL[4];
#pragma unroll
    for (int f = 0; f < 4; f++)
#pragma unroll
        for (int r = 0; r < 4; r++) accL[f][r] = 0.f;
#pragma unroll
    for (int half = 0; half < 2; half++) {
#pragma unroll
        for (int f = 0; f < 4; f++)
#pragma unroll
            for (int r = 0; r < 4; r++)
                su_w[(g * 4 + r) * 72 + f * 16 + col] = o1v[half * 4 + f][r];
        f16x8 ao[2];
#pragma unroll
        for (int kc = 0; kc < 2; kc++)
            ao[kc] = *(const f16x8*)&su_w[col * 72 + kc * 32 + g * 8];
#pragma unroll
        for (int kc = 0; kc < 2; kc++) {
            int kglob = half * 2 + kc;
#pragma unroll
            for (int f = 0; f < 4; f++) {
                f16x8 bw = *(const f16x8*)
                    &slabW[(f * 16 + col) * 136 + kglob * 32 + g * 8];
                accL[f] = __builtin_amdgcn_mfma_f32_16x16x32_f16(
                    ao[kc], bw, accL[f], 0, 0, 0);
            }
        }
    }
    // ---- softmax over s + einsum ----
    float outv[4];
#pragma unroll
    for (int f = 0; f < 4; f++) {
        float mx = fmaxf(fmaxf(accL[f][0], accL[f][1]),
                         fmaxf(accL[f][2], accL[f][3]));
        mx = fmaxf(mx, __shfl_xor(mx, 16, 64));
        mx = fmaxf(mx, __shfl_xor(mx, 32, 64));
        float sum = 0.f, part = 0.f;
#pragma unroll
        for (int r = 0; r < 4; r++) {
            float e = __expf(accL[f][r] - mx);
            sum += e;
            part = fmaf(e, vvr[f][r], part);
        }
        sum += __shfl_xor(sum, 16, 64);
        sum += __shfl_xor(sum, 32, 64);
        part += __shfl_xor(part, 16, 64);
        part += __shfl_xor(part, 32, 64);
        outv[f] = part / sum;
    }
    float val = (g == 0) ? outv[0]
              : (g == 1) ? outv[1]
              : (g == 2) ? outv[2] : outv[3];
    attn[q * 64 + lane] = val;
}

// ---------------------------------------------------------------------------
// K3: FUSED MFMA-f16 head (verbatim R7): out = LN(relu(bn(relu(bn(
// [feats,attn]@Wc1))@Wc2))@Wc3+bc3). 256 blocks x 256 thr, 32 rows/block.
// ---------------------------------------------------------------------------
__global__ __launch_bounds__(256) void head_kernel(
    const float* __restrict__ feats, const float* __restrict__ attn,
    const float* __restrict__ Wc1, const float* __restrict__ cg1,
    const float* __restrict__ cb1, const float* __restrict__ Wc2,
    const float* __restrict__ cg2, const float* __restrict__ cb2,
    const float* __restrict__ Wc3, const float* __restrict__ bc3,
    const float* __restrict__ lng, const float* __restrict__ lnb,
    float* __restrict__ out)
{
    __shared__ _Float16 sWt[128 * 136];
    __shared__ _Float16 sX[2][16 * 136];
    __shared__ _Float16 sY[2][16 * 136];
    __shared__ float sOut[32 * 68];
    __shared__ float sga[128], sba[128], sgb[128], sbb[128];
    __shared__ float sbc3[64], slng[64], slnb[64];

    const int t = threadIdx.x;
    const int lane = t & 63;
    const int wv = t >> 6;
    const int rg = wv >> 1, hf = wv & 1;
    const int col = lane & 15, g = lane >> 4;
    const int row0 = blockIdx.x * 32;

    {
        int r = t >> 3, c0 = (t & 7) * 16;
        const float* src = (c0 < 64) ? (feats + (row0 + r) * 64 + c0)
                                     : (attn + (row0 + r) * 64 + (c0 - 64));
        _Float16* dst = &sX[r >> 4][(r & 15) * 136 + c0];
#pragma unroll
        for (int i = 0; i < 4; i++) {
            float4 v = ((const float4*)src)[i];
            dst[i * 4 + 0] = (_Float16)v.x;
            dst[i * 4 + 1] = (_Float16)v.y;
            dst[i * 4 + 2] = (_Float16)v.z;
            dst[i * 4 + 3] = (_Float16)v.w;
        }
    }
    auto stageW128 = [&](const float* W) {
        int c = t >> 1, ob = (t & 1) * 64;
        const float4* src = (const float4*)(W + c * 128 + ob);
#pragma unroll
        for (int i = 0; i < 16; i++) {
            float4 w = src[i];
            _Float16* d = &sWt[(ob + i * 4) * 136 + c];
            d[0 * 136] = (_Float16)w.x; d[1 * 136] = (_Float16)w.y;
            d[2 * 136] = (_Float16)w.z; d[3 * 136] = (_Float16)w.w;
        }
    };
    stageW128(Wc1);
    if (t < 128) {
        sga[t] = cg1[t] * BN_INV; sba[t] = cb1[t];
        sgb[t] = cg2[t] * BN_INV; sbb[t] = cb2[t];
    } else if (t < 192) {
        int o = t - 128;
        sbc3[o] = bc3[o]; slng[o] = lng[o]; slnb[o] = lnb[o];
    }
    __syncthreads();
    {
        f16x8 ax[4];
#pragma unroll
        for (int kc = 0; kc < 4; kc++)
            ax[kc] = *(const f16x8*)&sX[rg][col * 136 + kc * 32 + g * 8];
        f32x4 acc[4];
#pragma unroll
        for (int ft = 0; ft < 4; ft++)
#pragma unroll
            for (int r = 0; r < 4; r++) acc[ft][r] = 0.f;
#pragma unroll
        for (int kc = 0; kc < 4; kc++)
#pragma unroll
            for (int ft = 0; ft < 4; ft++) {
                int n = hf * 64 + ft * 16 + col;
                f16x8 bw = *(const f16x8*)&sWt[n * 136 + kc * 32 + g * 8];
                acc[ft] = __builtin_amdgcn_mfma_f32_16x16x32_f16(ax[kc], bw,
                                                                 acc[ft],
                                                                 0, 0, 0);
            }
#pragma unroll
        for (int ft = 0; ft < 4; ft++)
#pragma unroll
            for (int r = 0; r < 4; r++) {
                int o = hf * 64 + ft * 16 + col;
                float v = fmaxf(acc[ft][r] * sga[o] + sba[o], 0.f);
                sY[rg][(g * 4 + r) * 136 + o] = (_Float16)v;
            }
    }
    __syncthreads();
    stageW128(Wc2);
    __syncthreads();
    {
        f16x8 ax[4];
#pragma unroll
        for (int kc = 0; kc < 4; kc++)
            ax[kc] = *(const f16x8*)&sY[rg][col * 136 + kc * 32 + g * 8];
        f32x4 acc[4];
#pragma unroll
        for (int ft = 0; ft < 4; ft++)
#pragma unroll
            for (int r = 0; r < 4; r++) acc[ft][r] = 0.f;
#pragma unroll
        for (int kc = 0; kc < 4; kc++)
#pragma unroll
            for (int ft = 0; ft < 4; ft++) {
                int n = hf * 64 + ft * 16 + col;
                f16x8 bw = *(const f16x8*)&sWt[n * 136 + kc * 32 + g * 8];
                acc[ft] = __builtin_amdgcn_mfma_f32_16x16x32_f16(ax[kc], bw,
                                                                 acc[ft],
                                                                 0, 0, 0);
            }
#pragma unroll
        for (int ft = 0; ft < 4; ft++)
#pragma unroll
            for (int r = 0; r < 4; r++) {
                int o = hf * 64 + ft * 16 + col;
                float v = fmaxf(acc[ft][r] * sgb[o] + sbb[o], 0.f);
                sX[rg][(g * 4 + r) * 136 + o] = (_Float16)v;
            }
    }
    __syncthreads();
    {
        int c = t >> 1, ob = (t & 1) * 32;
        const float4* src = (const float4*)(Wc3 + c * 64 + ob);
#pragma unroll
        for (int i = 0; i < 8; i++) {
            float4 w = src[i];
            _Float16* d = &sWt[(ob + i * 4) * 136 + c];
            d[0 * 136] = (_Float16)w.x; d[1 * 136] = (_Float16)w.y;
            d[2 * 136] = (_Float16)w.z; d[3 * 136] = (_Float16)w.w;
        }
    }
    __syncthreads();
    {
        f16x8 ax[4];
#pragma unroll
        for (int kc = 0; kc < 4; kc++)
            ax[kc] = *(const f16x8*)&sX[rg][col * 136 + kc * 32 + g * 8];
#pragma unroll
        for (int ft = 0; ft < 2; ft++) {
            int n = hf * 32 + ft * 16 + col;
            f32x4 acc;
            float bias = sbc3[n];
#pragma unroll
            for (int r = 0; r < 4; r++) acc[r] = bias;
#pragma unroll
            for (int kc = 0; kc < 4; kc++) {
                f16x8 bw = *(const f16x8*)&sWt[n * 136 + kc * 32 + g * 8];
                acc = __builtin_amdgcn_mfma_f32_16x16x32_f16(ax[kc], bw, acc,
                                                             0, 0, 0);
            }
#pragma unroll
            for (int r = 0; r < 4; r++)
                sOut[(rg * 16 + g * 4 + r) * 68 + n] = acc[r];
        }
    }
    __syncthreads();
    {
        int r = t >> 3, o0 = (t & 7) * 8;
        float v[8];
        float s1 = 0.f, s2 = 0.f;
#pragma unroll
        for (int k = 0; k < 8; k++) {
            v[k] = sOut[r * 68 + o0 + k];
            s1 += v[k];
            s2 = fmaf(v[k], v[k], s2);
        }
#pragma unroll
        for (int d = 1; d < 8; d <<= 1) {
            s1 += __shfl_xor(s1, d, 8);
            s2 += __shfl_xor(s2, d, 8);
        }
        float m = s1 * (1.f / 64.f);
        float var = s2 * (1.f / 64.f) - m * m;
        float inv = 1.f / sqrtf(var + LN_EPS);
        float* dst = out + (row0 + r) * 64;
#pragma unroll
        for (int k = 0; k < 8; k++) {
            int o = o0 + k;
            dst[o] = (v[k] - m) * inv * slng[o] + slnb[o];
        }
    }
}

// ---------------------------------------------------------------------------
extern "C" void kernel_launch(void* const* d_in, const int* in_sizes, int n_in,
                              void* d_out, int out_size, void* d_ws,
                              size_t ws_size, hipStream_t stream)
{
    const int* indices = (const int*)d_in[0];
    const float* feats = (const float*)d_in[1];
    const float* Wq = (const float*)d_in[2];
    const float* bq = (const float*)d_in[3];
    const float* Wk = (const float*)d_in[4];
    const float* bk = (const float*)d_in[5];
    const float* Wv = (const float*)d_in[6];
    const float* bv = (const float*)d_in[7];
    const float* Wp1 = (const float*)d_in[8];
    const float* pg = (const float*)d_in[9];
    const float* pb = (const float*)d_in[10];
    const float* Wp2 = (const float*)d_in[11];
    const float* bp2 = (const float*)d_in[12];
    const float* wg1 = (const float*)d_in[13];
    const float* wb1 = (const float*)d_in[14];
    const float* Ww1 = (const float*)d_in[15];
    const float* wg2 = (const float*)d_in[16];
    const float* wb2 = (const float*)d_in[17];
    const float* Ww2 = (const float*)d_in[18];
    const float* Wc1 = (const float*)d_in[20];
    const float* cg1 = (const float*)d_in[21];
    const float* cb1 = (const float*)d_in[22];
    const float* Wc2 = (const float*)d_in[23];
    const float* cg2 = (const float*)d_in[24];
    const float* cb2 = (const float*)d_in[25];
    const float* Wc3 = (const float*)d_in[26];
    const float* bc3 = (const float*)d_in[27];
    const float* lng = (const float*)d_in[28];
    const float* lnb = (const float*)d_in[29];

    float* out = (float*)d_out;
    float* ws = (float*)d_ws;
    float* xq = ws;
    float* xk = xq + N * C;
    float* xv = xk + N * C;
    float* attn = xv + N * C;
    int* knn = (int*)(attn + N * C);

    qkv_knn_kernel<<<544, 1024, 32768, stream>>>(
        (const int4*)indices, knn, feats, Wq, bq, Wk, bk, Wv, bv, xq, xk, xv);
    attn_kernel<<<1024, 512, 0, stream>>>(
        (const int4*)indices, knn, xq, xk, xv, Wp1, pg, pb, Wp2, bp2, wg1,
        wb1, Ww1, wg2, wb2, Ww2, attn);
    head_kernel<<<256, 256, 0, stream>>>(feats, attn, Wc1, cg1, cb1, Wc2, cg2,
                                         cb2, Wc3, bc3, lng, lnb, out);
}

// Round 10
// 201.749 us; speedup vs baseline: 1.3037x; 1.3037x over previous
//
#include <hip/hip_runtime.h>

#define N 8192
#define C 64
#define S 16

static constexpr float BN_INV = 0.9999950000374997f; // 1/sqrt(1+1e-5)
static constexpr float LN_EPS = 1e-5f;

typedef _Float16 f16x8 __attribute__((ext_vector_type(8)));
typedef float f32x4 __attribute__((ext_vector_type(4)));

__device__ __forceinline__ void sort2(unsigned& x, unsigned& y)
{
    unsigned lo = min(x, y);
    unsigned hi = max(x, y);
    x = lo;
    y = hi;
}

// ---------------------------------------------------------------------------
// K1: FUSED knn + qkv + weight-prep. Blocks [0,1024): exact 16-NN (R7).
// Blocks [1024,1088): MFMA-f16 qkv. Block 1088: transpose-convert Ww1/Ww2/
// Wc1/Wc2/Wc3 to f16 n-major/k-contiguous in workspace so K2/K3 can stage
// weights with vector copies instead of scalar f32->f16 converts. The prep
// block rides free under knn's ~60us latency shadow.
// ---------------------------------------------------------------------------
__global__ __launch_bounds__(512) void qkv_knn_kernel(
    const int4* __restrict__ idx4, int* __restrict__ knn_out,
    const float* __restrict__ feats,
    const float* __restrict__ Wq, const float* __restrict__ bq,
    const float* __restrict__ Wk, const float* __restrict__ bk,
    const float* __restrict__ Wv, const float* __restrict__ bv,
    float* __restrict__ xq, float* __restrict__ xk, float* __restrict__ xv,
    const float* __restrict__ Ww1, const float* __restrict__ Ww2,
    const float* __restrict__ Wc1, const float* __restrict__ Wc2,
    const float* __restrict__ Wc3,
    _Float16* __restrict__ W1tG, _Float16* __restrict__ W2tG,
    _Float16* __restrict__ Wc1tG, _Float16* __restrict__ Wc2tG,
    _Float16* __restrict__ Wc3tG)
{
    extern __shared__ char smem[];
    const int t = threadIdx.x;
    const int lane = t & 63;
    const int wv = t >> 6;
    if (blockIdx.x < 1024) {
        unsigned* pk = (unsigned*)smem;
        const int q = blockIdx.x * 8 + wv;
#pragma unroll
        for (int i = 0; i < 16; i++) {
            int j = i * 512 + t;
            int4 c = idx4[j];
            pk[j] = (unsigned)c.y | ((unsigned)c.z << 8) |
                    ((unsigned)c.w << 16);
        }
        const int4 qc = idx4[q];
        const int qx = qc.y, qy = qc.z, qz = qc.w;
        const unsigned qq = (unsigned)(qx * qx + qy * qy + qz * qz);
#if __has_builtin(__builtin_amdgcn_udot4)
        const unsigned qpk2 = (unsigned)(2 * qx) | ((unsigned)(2 * qy) << 8) |
                              ((unsigned)(2 * qz) << 16);
#endif
        unsigned a0 = 0xFFFFFFFFu, a1 = 0xFFFFFFFFu, a2 = 0xFFFFFFFFu,
                 a3 = 0xFFFFFFFFu;
        unsigned b0 = 0xFFFFFFFFu, b1 = 0xFFFFFFFFu, b2 = 0xFFFFFFFFu,
                 b3 = 0xFFFFFFFFu;
        __syncthreads();
#pragma unroll 4
        for (int i = 0; i < 64; ++i) {
            int jA = i * 64 + lane;
            int jB = (i + 64) * 64 + lane;
            unsigned pA = pk[jA];
            unsigned pB = pk[jB];
#if __has_builtin(__builtin_amdgcn_udot4)
            unsigned d2A = __builtin_amdgcn_udot4(pA, pA, qq, false) -
                           __builtin_amdgcn_udot4(pA, qpk2, 0u, false);
            unsigned d2B = __builtin_amdgcn_udot4(pB, pB, qq, false) -
                           __builtin_amdgcn_udot4(pB, qpk2, 0u, false);
#else
            int xa = (int)(pA & 255u), ya = (int)((pA >> 8) & 255u),
                za = (int)(pA >> 16);
            int xb = (int)(pB & 255u), yb = (int)((pB >> 8) & 255u),
                zb = (int)(pB >> 16);
            int dxa = xa - qx, dya = ya - qy, dza = za - qz;
            int dxb = xb - qx, dyb = yb - qy, dzb = zb - qz;
            unsigned d2A = (unsigned)(dxa * dxa + dya * dya + dza * dza);
            unsigned d2B = (unsigned)(dxb * dxb + dyb * dyb + dzb * dzb);
#endif
            unsigned keyA = (d2A << 13) + (unsigned)jA;
            unsigned keyB = (d2B << 13) + (unsigned)jB;
            a3 = min(a3, keyA);
            sort2(a2, a3); sort2(a1, a2); sort2(a0, a1);
            b3 = min(b3, keyB);
            sort2(b2, b3); sort2(b1, b2); sort2(b0, b1);
        }
        unsigned t0 = min(a0, b3), t1 = min(a1, b2), t2 = min(a2, b1),
                 t3 = min(a3, b0);
        sort2(t0, t2); sort2(t1, t3); sort2(t0, t1); sort2(t2, t3);
        sort2(t1, t2);
        const unsigned t3pre = t3;
        unsigned g16 = 0;
        for (int r = 0; r < 16; ++r) {
            unsigned m = t0;
            m = min(m, (unsigned)__shfl_xor((int)m, 1, 64));
            m = min(m, (unsigned)__shfl_xor((int)m, 2, 64));
            m = min(m, (unsigned)__shfl_xor((int)m, 4, 64));
            m = min(m, (unsigned)__shfl_xor((int)m, 8, 64));
            m = min(m, (unsigned)__shfl_xor((int)m, 16, 64));
            m = min(m, (unsigned)__shfl_xor((int)m, 32, 64));
            if (lane == r) knn_out[q * 16 + r] = (int)(m & 8191u);
            bool win = (t0 == m);
            t0 = win ? t1 : t0;
            t1 = win ? t2 : t1;
            t2 = win ? t3 : t2;
            t3 = win ? 0xFFFFFFFFu : t3;
            g16 = m;
        }
        unsigned long long bad = __ballot(t3pre < g16);
        if (bad) {
            unsigned c0 = 0xFFFFFFFFu, c1 = 0xFFFFFFFFu, c2 = 0xFFFFFFFFu,
                     c3 = 0xFFFFFFFFu, c4 = 0xFFFFFFFFu, c5 = 0xFFFFFFFFu,
                     c6 = 0xFFFFFFFFu, c7 = 0xFFFFFFFFu, c8 = 0xFFFFFFFFu,
                     c9 = 0xFFFFFFFFu, c10 = 0xFFFFFFFFu, c11 = 0xFFFFFFFFu,
                     c12 = 0xFFFFFFFFu, c13 = 0xFFFFFFFFu, c14 = 0xFFFFFFFFu,
                     c15 = 0xFFFFFFFFu;
            for (int i = 0; i < 128; ++i) {
                int j = i * 64 + lane;
                int4 cd = idx4[j];
                int dx = cd.y - qx, dy = cd.z - qy, dz = cd.w - qz;
                unsigned d2 = (unsigned)(dx * dx + dy * dy + dz * dz);
                unsigned key = (d2 << 13) + (unsigned)j;
                c15 = min(c15, key);
                sort2(c14, c15); sort2(c13, c14); sort2(c12, c13);
                sort2(c11, c12); sort2(c10, c11); sort2(c9, c10);
                sort2(c8, c9);   sort2(c7, c8);   sort2(c6, c7);
                sort2(c5, c6);   sort2(c4, c5);   sort2(c3, c4);
                sort2(c2, c3);   sort2(c1, c2);   sort2(c0, c1);
            }
            for (int r = 0; r < 16; ++r) {
                unsigned m = c0;
                m = min(m, (unsigned)__shfl_xor((int)m, 1, 64));
                m = min(m, (unsigned)__shfl_xor((int)m, 2, 64));
                m = min(m, (unsigned)__shfl_xor((int)m, 4, 64));
                m = min(m, (unsigned)__shfl_xor((int)m, 8, 64));
                m = min(m, (unsigned)__shfl_xor((int)m, 16, 64));
                m = min(m, (unsigned)__shfl_xor((int)m, 32, 64));
                if (lane == r) knn_out[q * 16 + r] = (int)(m & 8191u);
                bool win = (c0 == m);
                c0 = win ? c1 : c0;    c1 = win ? c2 : c1;
                c2 = win ? c3 : c2;    c3 = win ? c4 : c3;
                c4 = win ? c5 : c4;    c5 = win ? c6 : c5;
                c6 = win ? c7 : c6;    c7 = win ? c8 : c7;
                c8 = win ? c9 : c8;    c9 = win ? c10 : c9;
                c10 = win ? c11 : c10; c11 = win ? c12 : c11;
                c12 = win ? c13 : c12; c13 = win ? c14 : c13;
                c14 = win ? c15 : c14; c15 = win ? 0xFFFFFFFFu : c15;
            }
        }
    } else if (blockIdx.x < 1088) {
        _Float16* sBt = (_Float16*)smem;
        float* sbias = (float*)(smem + 192 * 72 * 2);
        const int col = lane & 15, g = lane >> 4;
        const int bid2 = blockIdx.x - 1024;
        const int row0w = bid2 * 128 + wv * 16;
        {
            const float* Ws[3] = {Wq, Wk, Wv};
#pragma unroll
            for (int m = 0; m < 3; m++) {
                int k = t >> 3, nb = (t & 7) * 8;
                const float4* src = (const float4*)(Ws[m] + k * 64 + nb);
                float4 w0 = src[0], w1 = src[1];
                _Float16* dst = &sBt[(m * 64 + nb) * 72 + k];
                dst[0 * 72] = (_Float16)w0.x; dst[1 * 72] = (_Float16)w0.y;
                dst[2 * 72] = (_Float16)w0.z; dst[3 * 72] = (_Float16)w0.w;
                dst[4 * 72] = (_Float16)w1.x; dst[5 * 72] = (_Float16)w1.y;
                dst[6 * 72] = (_Float16)w1.z; dst[7 * 72] = (_Float16)w1.w;
            }
            if (t < 64) sbias[t] = bq[t];
            else if (t < 128) sbias[t] = bk[t - 64];
            else if (t < 192) sbias[t] = bv[t - 128];
        }
        __syncthreads();
        f16x8 au[2];
#pragma unroll
        for (int kc = 0; kc < 2; kc++) {
            const float4* src = (const float4*)
                (feats + (row0w + col) * 64 + kc * 32 + g * 8);
            float4 v0 = src[0], v1 = src[1];
            au[kc][0] = (_Float16)v0.x; au[kc][1] = (_Float16)v0.y;
            au[kc][2] = (_Float16)v0.z; au[kc][3] = (_Float16)v0.w;
            au[kc][4] = (_Float16)v1.x; au[kc][5] = (_Float16)v1.y;
            au[kc][6] = (_Float16)v1.z; au[kc][7] = (_Float16)v1.w;
        }
        float* outs[3] = {xq, xk, xv};
#pragma unroll
        for (int f = 0; f < 12; f++) {
            f32x4 acc;
            float bias = sbias[f * 16 + col];
#pragma unroll
            for (int r = 0; r < 4; r++) acc[r] = bias;
#pragma unroll
            for (int kc = 0; kc < 2; kc++) {
                f16x8 bw = *(const f16x8*)
                    &sBt[(f * 16 + col) * 72 + kc * 32 + g * 8];
                acc = __builtin_amdgcn_mfma_f32_16x16x32_f16(au[kc], bw, acc,
                                                             0, 0, 0);
            }
            float* o = outs[f >> 2];
            int cg = (f & 3) * 16 + col;
#pragma unroll
            for (int r = 0; r < 4; r++)
                o[(row0w + g * 4 + r) * 64 + cg] = acc[r];
        }
    } else {
        // weight prep: WT[n][k] (k-contiguous) = W[k][n], f16
        for (int o = t; o < 8192; o += 512) {         // Ww1: 64x128
            int n = o >> 6, k = o & 63;
            W1tG[o] = (_Float16)Ww1[k * 128 + n];
        }
        for (int o = t; o < 8192; o += 512) {         // Ww2: 128x64
            int n = o >> 7, k = o & 127;
            W2tG[o] = (_Float16)Ww2[k * 64 + n];
        }
        for (int o = t; o < 16384; o += 512) {        // Wc1: 128x128
            int n = o >> 7, k = o & 127;
            Wc1tG[o] = (_Float16)Wc1[k * 128 + n];
        }
        for (int o = t; o < 16384; o += 512) {        // Wc2: 128x128
            int n = o >> 7, k = o & 127;
            Wc2tG[o] = (_Float16)Wc2[k * 128 + n];
        }
        for (int o = t; o < 8192; o += 512) {         // Wc3: 128x64
            int n = o >> 7, k = o & 127;
            Wc3tG[o] = (_Float16)Wc3[k * 64 + n];
        }
    }
}

// ---------------------------------------------------------------------------
// K2: MFMA vector-attention (R7 structure; best known). 1024 x 512; one
// query per wave. Weight staging now a vector copy from pre-transposed f16
// (8x fewer staging instructions, half the bytes). bw2 dropped (cancels in
// softmax over s).
// ---------------------------------------------------------------------------
__global__ __launch_bounds__(512, 4) void attn_kernel(
    const int4* __restrict__ idx4, const int* __restrict__ knn,
    const float* __restrict__ xq, const float* __restrict__ xk,
    const float* __restrict__ xv,
    const float* __restrict__ Wp1, const float* __restrict__ pg,
    const float* __restrict__ pb, const float* __restrict__ Wp2,
    const float* __restrict__ bp2,
    const float* __restrict__ wg1, const float* __restrict__ wb1,
    const _Float16* __restrict__ W1tG,
    const float* __restrict__ wg2, const float* __restrict__ wb2,
    const _Float16* __restrict__ W2tG,
    float* __restrict__ attn)
{
    __shared__ _Float16 sW1t[128 * 72];
    __shared__ _Float16 sW2t[64 * 136];
    __shared__ _Float16 sscr[8][16 * 136];
    __shared__ float sWp1[48], sPg[16], sPb[16];

    const int t = threadIdx.x;
    const int lane = t & 63;
    const int wv = t >> 6;
    const int col = lane & 15, g = lane >> 4;
    const int q = blockIdx.x * 8 + wv;

    const int jA = knn[q * 16 + col];
    const int4 jC = *(const int4*)(knn + q * 16 + g * 4);
    const int jr[4] = {jC.x, jC.y, jC.z, jC.w};
    const int4 pc = idx4[jA];
    const int4 qc = idx4[q];
    float xqv[4], xkv[4][4], xvv[4][4];
#pragma unroll
    for (int f = 0; f < 4; f++) xqv[f] = xq[q * 64 + f * 16 + col];
#pragma unroll
    for (int r = 0; r < 4; r++)
#pragma unroll
        for (int f = 0; f < 4; f++) {
            xkv[r][f] = xk[jr[r] * 64 + f * 16 + col];
            xvv[r][f] = xv[jr[r] * 64 + f * 16 + col];
        }

    // vectorized weight staging from pre-transposed f16
    for (int i = t; i < 1024; i += 512) {
        int n = i >> 3, ko = i & 7;
        *(f16x8*)&sW1t[n * 72 + ko * 8] =
            *(const f16x8*)&W1tG[n * 64 + ko * 8];
    }
    for (int i = t; i < 1024; i += 512) {
        int m = i >> 4, ko = i & 15;
        *(f16x8*)&sW2t[m * 136 + ko * 8] =
            *(const f16x8*)&W2tG[m * 128 + ko * 8];
    }
    if (t < 48) sWp1[t] = Wp1[t];
    if (t < 16) { sPg[t] = pg[t] * BN_INV; sPb[t] = pb[t]; }

    float g1c[4], b1c[4], bp2c[4], g2c[8], b2c[8];
#pragma unroll
    for (int f = 0; f < 4; f++) {
        int c = f * 16 + col;
        g1c[f] = wg1[c] * BN_INV; b1c[f] = wb1[c];
        bp2c[f] = bp2[c];
    }
#pragma unroll
    for (int f = 0; f < 8; f++) {
        int o = f * 16 + col;
        g2c[f] = wg2[o] * BN_INV; b2c[f] = wb2[o];
    }
    f16x8 bP[4];
#pragma unroll
    for (int f = 0; f < 4; f++) {
#pragma unroll
        for (int j = 0; j < 8; j++) {
            int h = g * 8 + j;
            bP[f][j] = (g < 2) ? (_Float16)Wp2[h * 64 + f * 16 + col]
                               : (_Float16)0.f;
        }
    }
    __syncthreads();

    _Float16* scr = sscr[wv];

    const float px = (float)(pc.y - qc.y);
    const float py = (float)(pc.z - qc.z);
    const float pz = (float)(pc.w - qc.w);
    f16x8 aph;
#pragma unroll
    for (int j = 0; j < 8; j++) {
        int h = g * 8 + j;
        float v = 0.f;
        if (g < 2) {
            v = px * sWp1[h] + py * sWp1[16 + h] + pz * sWp1[32 + h];
            v = fmaxf(v * sPg[h] + sPb[h], 0.f);
        }
        aph[j] = (_Float16)v;
    }
    f32x4 pr[4];
#pragma unroll
    for (int f = 0; f < 4; f++) {
        f32x4 cini;
#pragma unroll
        for (int r = 0; r < 4; r++) cini[r] = bp2c[f];
        pr[f] = __builtin_amdgcn_mfma_f32_16x16x32_f16(aph, bP[f], cini,
                                                       0, 0, 0);
    }
    f32x4 vvr[4];
#pragma unroll
    for (int r = 0; r < 4; r++) {
#pragma unroll
        for (int f = 0; f < 4; f++) {
            float w0 = xkv[r][f] - xqv[f] + pr[f][r];
            float uu = fmaxf(w0 * g1c[f] + b1c[f], 0.f);
            scr[(g * 4 + r) * 72 + f * 16 + col] = (_Float16)uu;
            vvr[f][r] = xvv[r][f] + pr[f][r];
        }
    }
    f16x8 au[2];
#pragma unroll
    for (int kc = 0; kc < 2; kc++)
        au[kc] = *(const f16x8*)&scr[col * 72 + kc * 32 + g * 8];
    f32x4 acc1[8];
#pragma unroll
    for (int f = 0; f < 8; f++)
#pragma unroll
        for (int r = 0; r < 4; r++) acc1[f][r] = 0.f;
#pragma unroll
    for (int kc = 0; kc < 2; kc++) {
#pragma unroll
        for (int f = 0; f < 8; f++) {
            f16x8 bw = *(const f16x8*)
                &sW1t[(f * 16 + col) * 72 + kc * 32 + g * 8];
            acc1[f] = __builtin_amdgcn_mfma_f32_16x16x32_f16(au[kc], bw,
                                                             acc1[f], 0, 0, 0);
        }
    }
#pragma unroll
    for (int f = 0; f < 8; f++)
#pragma unroll
        for (int r = 0; r < 4; r++) {
            float o1 = fmaxf(acc1[f][r] * g2c[f] + b2c[f], 0.f);
            scr[(g * 4 + r) * 136 + f * 16 + col] = (_Float16)o1;
        }
    f16x8 ao[4];
#pragma unroll
    for (int kc = 0; kc < 4; kc++)
        ao[kc] = *(const f16x8*)&scr[col * 136 + kc * 32 + g * 8];
    f32x4 accL[4];
#pragma unroll
    for (int f = 0; f < 4; f++)
#pragma unroll
        for (int r = 0; r < 4; r++) accL[f][r] = 0.f;
#pragma unroll
    for (int kc = 0; kc < 4; kc++) {
#pragma unroll
        for (int f = 0; f < 4; f++) {
            f16x8 bw = *(const f16x8*)
                &sW2t[(f * 16 + col) * 136 + kc * 32 + g * 8];
            accL[f] = __builtin_amdgcn_mfma_f32_16x16x32_f16(ao[kc], bw,
                                                             accL[f], 0, 0, 0);
        }
    }
    float outv[4];
#pragma unroll
    for (int f = 0; f < 4; f++) {
        float mx = fmaxf(fmaxf(accL[f][0], accL[f][1]),
                         fmaxf(accL[f][2], accL[f][3]));
        mx = fmaxf(mx, __shfl_xor(mx, 16, 64));
        mx = fmaxf(mx, __shfl_xor(mx, 32, 64));
        float sum = 0.f, part = 0.f;
#pragma unroll
        for (int r = 0; r < 4; r++) {
            float e = __expf(accL[f][r] - mx);
            sum += e;
            part = fmaf(e, vvr[f][r], part);
        }
        sum += __shfl_xor(sum, 16, 64);
        sum += __shfl_xor(sum, 32, 64);
        part += __shfl_xor(part, 16, 64);
        part += __shfl_xor(part, 32, 64);
        outv[f] = part / sum;
    }
    float val = (g == 0) ? outv[0]
              : (g == 1) ? outv[1]
              : (g == 2) ? outv[2] : outv[3];
    attn[q * 64 + lane] = val;
}

// ---------------------------------------------------------------------------
// K3: FUSED MFMA-f16 head (R7 structure), weights staged from pre-transposed
// f16 via vector copies.
// ---------------------------------------------------------------------------
__global__ __launch_bounds__(256) void head_kernel(
    const float* __restrict__ feats, const float* __restrict__ attn,
    const _Float16* __restrict__ Wc1tG, const float* __restrict__ cg1,
    const float* __restrict__ cb1, const _Float16* __restrict__ Wc2tG,
    const float* __restrict__ cg2, const float* __restrict__ cb2,
    const _Float16* __restrict__ Wc3tG, const float* __restrict__ bc3,
    const float* __restrict__ lng, const float* __restrict__ lnb,
    float* __restrict__ out)
{
    __shared__ _Float16 sWt[128 * 136];
    __shared__ _Float16 sX[2][16 * 136];
    __shared__ _Float16 sY[2][16 * 136];
    __shared__ float sOut[32 * 68];
    __shared__ float sga[128], sba[128], sgb[128], sbb[128];
    __shared__ float sbc3[64], slng[64], slnb[64];

    const int t = threadIdx.x;
    const int lane = t & 63;
    const int wv = t >> 6;
    const int rg = wv >> 1, hf = wv & 1;
    const int col = lane & 15, g = lane >> 4;
    const int row0 = blockIdx.x * 32;

    {
        int r = t >> 3, c0 = (t & 7) * 16;
        const float* src = (c0 < 64) ? (feats + (row0 + r) * 64 + c0)
                                     : (attn + (row0 + r) * 64 + (c0 - 64));
        _Float16* dst = &sX[r >> 4][(r & 15) * 136 + c0];
#pragma unroll
        for (int i = 0; i < 4; i++) {
            float4 v = ((const float4*)src)[i];
            dst[i * 4 + 0] = (_Float16)v.x;
            dst[i * 4 + 1] = (_Float16)v.y;
            dst[i * 4 + 2] = (_Float16)v.z;
            dst[i * 4 + 3] = (_Float16)v.w;
        }
    }
    auto stageWT = [&](const _Float16* WT, int chunks) {
        for (int i = t; i < chunks; i += 256) {
            int n = i >> 4, ko = i & 15;
            *(f16x8*)&sWt[n * 136 + ko * 8] =
                *(const f16x8*)&WT[n * 128 + ko * 8];
        }
    };
    stageWT(Wc1tG, 2048);
    if (t < 128) {
        sga[t] = cg1[t] * BN_INV; sba[t] = cb1[t];
        sgb[t] = cg2[t] * BN_INV; sbb[t] = cb2[t];
    } else if (t < 192) {
        int o = t - 128;
        sbc3[o] = bc3[o]; slng[o] = lng[o]; slnb[o] = lnb[o];
    }
    __syncthreads();
    {
        f16x8 ax[4];
#pragma unroll
        for (int kc = 0; kc < 4; kc++)
            ax[kc] = *(const f16x8*)&sX[rg][col * 136 + kc * 32 + g * 8];
        f32x4 acc[4];
#pragma unroll
        for (int ft = 0; ft < 4; ft++)
#pragma unroll
            for (int r = 0; r < 4; r++) acc[ft][r] = 0.f;
#pragma unroll
        for (int kc = 0; kc < 4; kc++)
#pragma unroll
            for (int ft = 0; ft < 4; ft++) {
                int n = hf * 64 + ft * 16 + col;
                f16x8 bw = *(const f16x8*)&sWt[n * 136 + kc * 32 + g * 8];
                acc[ft] = __builtin_amdgcn_mfma_f32_16x16x32_f16(ax[kc], bw,
                                                                 acc[ft],
                                                                 0, 0, 0);
            }
#pragma unroll
        for (int ft = 0; ft < 4; ft++)
#pragma unroll
            for (int r = 0; r < 4; r++) {
                int o = hf * 64 + ft * 16 + col;
                float v = fmaxf(acc[ft][r] * sga[o] + sba[o], 0.f);
                sY[rg][(g * 4 + r) * 136 + o] = (_Float16)v;
            }
    }
    __syncthreads();
    stageWT(Wc2tG, 2048);
    __syncthreads();
    {
        f16x8 ax[4];
#pragma unroll
        for (int kc = 0; kc < 4; kc++)
            ax[kc] = *(const f16x8*)&sY[rg][col * 136 + kc * 32 + g * 8];
        f32x4 acc[4];
#pragma unroll
        for (int ft = 0; ft < 4; ft++)
#pragma unroll
            for (int r = 0; r < 4; r++) acc[ft][r] = 0.f;
#pragma unroll
        for (int kc = 0; kc < 4; kc++)
#pragma unroll
            for (int ft = 0; ft < 4; ft++) {
                int n = hf * 64 + ft * 16 + col;
                f16x8 bw = *(const f16x8*)&sWt[n * 136 + kc * 32 + g * 8];
                acc[ft] = __builtin_amdgcn_mfma_f32_16x16x32_f16(ax[kc], bw,
                                                                 acc[ft],
                                                                 0, 0, 0);
            }
#pragma unroll
        for (int ft = 0; ft < 4; ft++)
#pragma unroll
            for (int r = 0; r < 4; r++) {
                int o = hf * 64 + ft * 16 + col;
                float v = fmaxf(acc[ft][r] * sgb[o] + sbb[o], 0.f);
                sX[rg][(g * 4 + r) * 136 + o] = (_Float16)v;
            }
    }
    __syncthreads();
    stageWT(Wc3tG, 1024);
    __syncthreads();
    {
        f16x8 ax[4];
#pragma unroll
        for (int kc = 0; kc < 4; kc++)
            ax[kc] = *(const f16x8*)&sX[rg][col * 136 + kc * 32 + g * 8];
#pragma unroll
        for (int ft = 0; ft < 2; ft++) {
            int n = hf * 32 + ft * 16 + col;
            f32x4 acc;
            float bias = sbc3[n];
#pragma unroll
            for (int r = 0; r < 4; r++) acc[r] = bias;
#pragma unroll
            for (int kc = 0; kc < 4; kc++) {
                f16x8 bw = *(const f16x8*)&sWt[n * 136 + kc * 32 + g * 8];
                acc = __builtin_amdgcn_mfma_f32_16x16x32_f16(ax[kc], bw, acc,
                                                             0, 0, 0);
            }
#pragma unroll
            for (int r = 0; r < 4; r++)
                sOut[(rg * 16 + g * 4 + r) * 68 + n] = acc[r];
        }
    }
    __syncthreads();
    {
        int r = t >> 3, o0 = (t & 7) * 8;
        float v[8];
        float s1 = 0.f, s2 = 0.f;
#pragma unroll
        for (int k = 0; k < 8; k++) {
            v[k] = sOut[r * 68 + o0 + k];
            s1 += v[k];
            s2 = fmaf(v[k], v[k], s2);
        }
#pragma unroll
        for (int d = 1; d < 8; d <<= 1) {
            s1 += __shfl_xor(s1, d, 8);
            s2 += __shfl_xor(s2, d, 8);
        }
        float m = s1 * (1.f / 64.f);
        float var = s2 * (1.f / 64.f) - m * m;
        float inv = 1.f / sqrtf(var + LN_EPS);
        float* dst = out + (row0 + r) * 64;
#pragma unroll
        for (int k = 0; k < 8; k++) {
            int o = o0 + k;
            dst[o] = (v[k] - m) * inv * slng[o] + slnb[o];
        }
    }
}

// ---------------------------------------------------------------------------
extern "C" void kernel_launch(void* const* d_in, const int* in_sizes, int n_in,
                              void* d_out, int out_size, void* d_ws,
                              size_t ws_size, hipStream_t stream)
{
    const int* indices = (const int*)d_in[0];
    const float* feats = (const float*)d_in[1];
    const float* Wq = (const float*)d_in[2];
    const float* bq = (const float*)d_in[3];
    const float* Wk = (const float*)d_in[4];
    const float* bk = (const float*)d_in[5];
    const float* Wv = (const float*)d_in[6];
    const float* bv = (const float*)d_in[7];
    const float* Wp1 = (const float*)d_in[8];
    const float* pg = (const float*)d_in[9];
    const float* pb = (const float*)d_in[10];
    const float* Wp2 = (const float*)d_in[11];
    const float* bp2 = (const float*)d_in[12];
    const float* wg1 = (const float*)d_in[13];
    const float* wb1 = (const float*)d_in[14];
    const float* Ww1 = (const float*)d_in[15];
    const float* wg2 = (const float*)d_in[16];
    const float* wb2 = (const float*)d_in[17];
    const float* Ww2 = (const float*)d_in[18];
    const float* Wc1 = (const float*)d_in[20];
    const float* cg1 = (const float*)d_in[21];
    const float* cb1 = (const float*)d_in[22];
    const float* Wc2 = (const float*)d_in[23];
    const float* cg2 = (const float*)d_in[24];
    const float* cb2 = (const float*)d_in[25];
    const float* Wc3 = (const float*)d_in[26];
    const float* bc3 = (const float*)d_in[27];
    const float* lng = (const float*)d_in[28];
    const float* lnb = (const float*)d_in[29];

    float* out = (float*)d_out;
    float* ws = (float*)d_ws;
    float* xq = ws;
    float* xk = xq + N * C;
    float* xv = xk + N * C;
    float* attn = xv + N * C;
    int* knn = (int*)(attn + N * C);
    _Float16* wt16 = (_Float16*)(knn + N * 16);
    _Float16* W1tG = wt16;              // 128 x 64
    _Float16* W2tG = W1tG + 8192;       // 64 x 128
    _Float16* Wc1tG = W2tG + 8192;      // 128 x 128
    _Float16* Wc2tG = Wc1tG + 16384;    // 128 x 128
    _Float16* Wc3tG = Wc2tG + 16384;    // 64 x 128

    qkv_knn_kernel<<<1089, 512, 32768, stream>>>(
        (const int4*)indices, knn, feats, Wq, bq, Wk, bk, Wv, bv, xq, xk, xv,
        Ww1, Ww2, Wc1, Wc2, Wc3, W1tG, W2tG, Wc1tG, Wc2tG, Wc3tG);
    attn_kernel<<<1024, 512, 0, stream>>>(
        (const int4*)indices, knn, xq, xk, xv, Wp1, pg, pb, Wp2, bp2, wg1,
        wb1, W1tG, wg2, wb2, W2tG, attn);
    head_kernel<<<256, 256, 0, stream>>>(feats, attn, Wc1tG, cg1, cb1, Wc2tG,
                                         cg2, cb2, Wc3tG, bc3, lng, lnb, out);
}

// Round 11
// 199.760 us; speedup vs baseline: 1.3166x; 1.0100x over previous
//
#include <hip/hip_runtime.h>

#define N 8192
#define C 64
#define S 16

static constexpr float BN_INV = 0.9999950000374997f; // 1/sqrt(1+1e-5)
static constexpr float LN_EPS = 1e-5f;

typedef _Float16 f16x8 __attribute__((ext_vector_type(8)));
typedef float f32x4 __attribute__((ext_vector_type(4)));

__device__ __forceinline__ void sort2(unsigned& x, unsigned& y)
{
    unsigned lo = min(x, y);
    unsigned hi = max(x, y);
    x = lo;
    y = hi;
}

__device__ __forceinline__ int mbcnt64(unsigned long long m)
{
    int lo = __builtin_amdgcn_mbcnt_lo((unsigned)m, 0);
    return __builtin_amdgcn_mbcnt_hi((unsigned)(m >> 32), lo);
}

// ---------------------------------------------------------------------------
// K1: FUSED knn + qkv + weight-prep. Blocks [0,1024): exact 16-NN set.
// KEY: downstream attn (softmax over s + einsum sum over s) is permutation-
// invariant in the neighbor axis, so we emit the top-16 SET in any order:
// radix-select the 16th-smallest key (29 ballot/popcount rounds, shallow
// deps) + ballot/mbcnt compaction — replaces the 16-round serial shuffle
// tournament (~96 dependent ds-swizzles). Exactness fallback as before.
// Blocks [1024,1088): MFMA-f16 qkv. Block 1088: f16 weight transposes.
// ---------------------------------------------------------------------------
__global__ __launch_bounds__(512) void qkv_knn_kernel(
    const int4* __restrict__ idx4, int* __restrict__ knn_out,
    const float* __restrict__ feats,
    const float* __restrict__ Wq, const float* __restrict__ bq,
    const float* __restrict__ Wk, const float* __restrict__ bk,
    const float* __restrict__ Wv, const float* __restrict__ bv,
    float* __restrict__ xq, float* __restrict__ xk, float* __restrict__ xv,
    const float* __restrict__ Ww1, const float* __restrict__ Ww2,
    const float* __restrict__ Wc1, const float* __restrict__ Wc2,
    const float* __restrict__ Wc3,
    _Float16* __restrict__ W1tG, _Float16* __restrict__ W2tG,
    _Float16* __restrict__ Wc1tG, _Float16* __restrict__ Wc2tG,
    _Float16* __restrict__ Wc3tG)
{
    extern __shared__ char smem[];
    const int t = threadIdx.x;
    const int lane = t & 63;
    const int wv = t >> 6;
    if (blockIdx.x < 1024) {
        unsigned* pk = (unsigned*)smem;
        const int q = blockIdx.x * 8 + wv;
#pragma unroll
        for (int i = 0; i < 16; i++) {
            int j = i * 512 + t;
            int4 c = idx4[j];
            pk[j] = (unsigned)c.y | ((unsigned)c.z << 8) |
                    ((unsigned)c.w << 16);
        }
        const int4 qc = idx4[q];
        const int qx = qc.y, qy = qc.z, qz = qc.w;
        const unsigned qq = (unsigned)(qx * qx + qy * qy + qz * qz);
#if __has_builtin(__builtin_amdgcn_udot4)
        const unsigned qpk2 = (unsigned)(2 * qx) | ((unsigned)(2 * qy) << 8) |
                              ((unsigned)(2 * qz) << 16);
#endif
        unsigned a0 = 0xFFFFFFFFu, a1 = 0xFFFFFFFFu, a2 = 0xFFFFFFFFu,
                 a3 = 0xFFFFFFFFu;
        unsigned b0 = 0xFFFFFFFFu, b1 = 0xFFFFFFFFu, b2 = 0xFFFFFFFFu,
                 b3 = 0xFFFFFFFFu;
        __syncthreads();
#pragma unroll 4
        for (int i = 0; i < 64; ++i) {
            int jA = i * 64 + lane;
            int jB = (i + 64) * 64 + lane;
            unsigned pA = pk[jA];
            unsigned pB = pk[jB];
#if __has_builtin(__builtin_amdgcn_udot4)
            unsigned d2A = __builtin_amdgcn_udot4(pA, pA, qq, false) -
                           __builtin_amdgcn_udot4(pA, qpk2, 0u, false);
            unsigned d2B = __builtin_amdgcn_udot4(pB, pB, qq, false) -
                           __builtin_amdgcn_udot4(pB, qpk2, 0u, false);
#else
            int xa = (int)(pA & 255u), ya = (int)((pA >> 8) & 255u),
                za = (int)(pA >> 16);
            int xb = (int)(pB & 255u), yb = (int)((pB >> 8) & 255u),
                zb = (int)(pB >> 16);
            int dxa = xa - qx, dya = ya - qy, dza = za - qz;
            int dxb = xb - qx, dyb = yb - qy, dzb = zb - qz;
            unsigned d2A = (unsigned)(dxa * dxa + dya * dya + dza * dza);
            unsigned d2B = (unsigned)(dxb * dxb + dyb * dyb + dzb * dzb);
#endif
            unsigned keyA = (d2A << 13) + (unsigned)jA;
            unsigned keyB = (d2B << 13) + (unsigned)jB;
            a3 = min(a3, keyA);
            sort2(a2, a3); sort2(a1, a2); sort2(a0, a1);
            b3 = min(b3, keyB);
            sort2(b2, b3); sort2(b1, b2); sort2(b0, b1);
        }
        // smallest 4 of the two sorted-4 lists
        unsigned t0 = min(a0, b3), t1 = min(a1, b2), t2 = min(a2, b1),
                 t3 = min(a3, b0);
        sort2(t0, t2); sort2(t1, t3); sort2(t0, t1); sort2(t2, t3);
        sort2(t1, t2);
        // radix-select T = 16th smallest of the 256 kept keys (keys < 2^29)
        unsigned prefix = 0u;
#pragma unroll
        for (int bit = 28; bit >= 0; --bit) {
            unsigned cand = prefix | (1u << bit);
            int c = __popcll(__ballot(t0 < cand)) +
                    __popcll(__ballot(t1 < cand)) +
                    __popcll(__ballot(t2 < cand)) +
                    __popcll(__ballot(t3 < cand));
            if (c < 16) prefix = cand;
        }
        const unsigned T = prefix;
        // compaction write of the 16 keys <= T (unordered — see header)
        {
            unsigned long long m0 = __ballot(t0 <= T);
            unsigned long long m1 = __ballot(t1 <= T);
            unsigned long long m2 = __ballot(t2 <= T);
            unsigned long long m3 = __ballot(t3 <= T);
            int base1 = __popcll(m0);
            int base2 = base1 + __popcll(m1);
            int base3 = base2 + __popcll(m2);
            int* dst = knn_out + q * 16;
            if (t0 <= T) dst[mbcnt64(m0)] = (int)(t0 & 8191u);
            if (t1 <= T) dst[base1 + mbcnt64(m1)] = (int)(t1 & 8191u);
            if (t2 <= T) dst[base2 + mbcnt64(m2)] = (int)(t2 & 8191u);
            if (t3 <= T) dst[base3 + mbcnt64(m3)] = (int)(t3 & 8191u);
        }
        // exactness: bad iff some lane may have dropped a key < T
        unsigned long long bad = __ballot(t3 < T);
        if (bad) {
            unsigned c0 = 0xFFFFFFFFu, c1 = 0xFFFFFFFFu, c2 = 0xFFFFFFFFu,
                     c3 = 0xFFFFFFFFu, c4 = 0xFFFFFFFFu, c5 = 0xFFFFFFFFu,
                     c6 = 0xFFFFFFFFu, c7 = 0xFFFFFFFFu, c8 = 0xFFFFFFFFu,
                     c9 = 0xFFFFFFFFu, c10 = 0xFFFFFFFFu, c11 = 0xFFFFFFFFu,
                     c12 = 0xFFFFFFFFu, c13 = 0xFFFFFFFFu, c14 = 0xFFFFFFFFu,
                     c15 = 0xFFFFFFFFu;
            for (int i = 0; i < 128; ++i) {
                int j = i * 64 + lane;
                int4 cd = idx4[j];
                int dx = cd.y - qx, dy = cd.z - qy, dz = cd.w - qz;
                unsigned d2 = (unsigned)(dx * dx + dy * dy + dz * dz);
                unsigned key = (d2 << 13) + (unsigned)j;
                c15 = min(c15, key);
                sort2(c14, c15); sort2(c13, c14); sort2(c12, c13);
                sort2(c11, c12); sort2(c10, c11); sort2(c9, c10);
                sort2(c8, c9);   sort2(c7, c8);   sort2(c6, c7);
                sort2(c5, c6);   sort2(c4, c5);   sort2(c3, c4);
                sort2(c2, c3);   sort2(c1, c2);   sort2(c0, c1);
            }
            for (int r = 0; r < 16; ++r) {
                unsigned m = c0;
                m = min(m, (unsigned)__shfl_xor((int)m, 1, 64));
                m = min(m, (unsigned)__shfl_xor((int)m, 2, 64));
                m = min(m, (unsigned)__shfl_xor((int)m, 4, 64));
                m = min(m, (unsigned)__shfl_xor((int)m, 8, 64));
                m = min(m, (unsigned)__shfl_xor((int)m, 16, 64));
                m = min(m, (unsigned)__shfl_xor((int)m, 32, 64));
                if (lane == r) knn_out[q * 16 + r] = (int)(m & 8191u);
                bool win = (c0 == m);
                c0 = win ? c1 : c0;    c1 = win ? c2 : c1;
                c2 = win ? c3 : c2;    c3 = win ? c4 : c3;
                c4 = win ? c5 : c4;    c5 = win ? c6 : c5;
                c6 = win ? c7 : c6;    c7 = win ? c8 : c7;
                c8 = win ? c9 : c8;    c9 = win ? c10 : c9;
                c10 = win ? c11 : c10; c11 = win ? c12 : c11;
                c12 = win ? c13 : c12; c13 = win ? c14 : c13;
                c14 = win ? c15 : c14; c15 = win ? 0xFFFFFFFFu : c15;
            }
        }
    } else if (blockIdx.x < 1088) {
        _Float16* sBt = (_Float16*)smem;
        float* sbias = (float*)(smem + 192 * 72 * 2);
        const int col = lane & 15, g = lane >> 4;
        const int bid2 = blockIdx.x - 1024;
        const int row0w = bid2 * 128 + wv * 16;
        {
            const float* Ws[3] = {Wq, Wk, Wv};
#pragma unroll
            for (int m = 0; m < 3; m++) {
                int k = t >> 3, nb = (t & 7) * 8;
                const float4* src = (const float4*)(Ws[m] + k * 64 + nb);
                float4 w0 = src[0], w1 = src[1];
                _Float16* dst = &sBt[(m * 64 + nb) * 72 + k];
                dst[0 * 72] = (_Float16)w0.x; dst[1 * 72] = (_Float16)w0.y;
                dst[2 * 72] = (_Float16)w0.z; dst[3 * 72] = (_Float16)w0.w;
                dst[4 * 72] = (_Float16)w1.x; dst[5 * 72] = (_Float16)w1.y;
                dst[6 * 72] = (_Float16)w1.z; dst[7 * 72] = (_Float16)w1.w;
            }
            if (t < 64) sbias[t] = bq[t];
            else if (t < 128) sbias[t] = bk[t - 64];
            else if (t < 192) sbias[t] = bv[t - 128];
        }
        __syncthreads();
        f16x8 au[2];
#pragma unroll
        for (int kc = 0; kc < 2; kc++) {
            const float4* src = (const float4*)
                (feats + (row0w + col) * 64 + kc * 32 + g * 8);
            float4 v0 = src[0], v1 = src[1];
            au[kc][0] = (_Float16)v0.x; au[kc][1] = (_Float16)v0.y;
            au[kc][2] = (_Float16)v0.z; au[kc][3] = (_Float16)v0.w;
            au[kc][4] = (_Float16)v1.x; au[kc][5] = (_Float16)v1.y;
            au[kc][6] = (_Float16)v1.z; au[kc][7] = (_Float16)v1.w;
        }
        float* outs[3] = {xq, xk, xv};
#pragma unroll
        for (int f = 0; f < 12; f++) {
            f32x4 acc;
            float bias = sbias[f * 16 + col];
#pragma unroll
            for (int r = 0; r < 4; r++) acc[r] = bias;
#pragma unroll
            for (int kc = 0; kc < 2; kc++) {
                f16x8 bw = *(const f16x8*)
                    &sBt[(f * 16 + col) * 72 + kc * 32 + g * 8];
                acc = __builtin_amdgcn_mfma_f32_16x16x32_f16(au[kc], bw, acc,
                                                             0, 0, 0);
            }
            float* o = outs[f >> 2];
            int cg = (f & 3) * 16 + col;
#pragma unroll
            for (int r = 0; r < 4; r++)
                o[(row0w + g * 4 + r) * 64 + cg] = acc[r];
        }
    } else {
        // weight prep: WT[n][k] (k-contiguous) = W[k][n], f16
        for (int o = t; o < 8192; o += 512) {         // Ww1: 64x128
            int n = o >> 6, k = o & 63;
            W1tG[o] = (_Float16)Ww1[k * 128 + n];
        }
        for (int o = t; o < 8192; o += 512) {         // Ww2: 128x64
            int n = o >> 7, k = o & 127;
            W2tG[o] = (_Float16)Ww2[k * 64 + n];
        }
        for (int o = t; o < 16384; o += 512) {        // Wc1: 128x128
            int n = o >> 7, k = o & 127;
            Wc1tG[o] = (_Float16)Wc1[k * 128 + n];
        }
        for (int o = t; o < 16384; o += 512) {        // Wc2: 128x128
            int n = o >> 7, k = o & 127;
            Wc2tG[o] = (_Float16)Wc2[k * 128 + n];
        }
        for (int o = t; o < 8192; o += 512) {         // Wc3: 128x64
            int n = o >> 7, k = o & 127;
            Wc3tG[o] = (_Float16)Wc3[k * 64 + n];
        }
    }
}

// ---------------------------------------------------------------------------
// K2: MFMA vector-attention (R7/R10 structure; best known). 1024 x 512; one
// query per wave. bw2 dropped (cancels in softmax over s).
// ---------------------------------------------------------------------------
__global__ __launch_bounds__(512, 4) void attn_kernel(
    const int4* __restrict__ idx4, const int* __restrict__ knn,
    const float* __restrict__ xq, const float* __restrict__ xk,
    const float* __restrict__ xv,
    const float* __restrict__ Wp1, const float* __restrict__ pg,
    const float* __restrict__ pb, const float* __restrict__ Wp2,
    const float* __restrict__ bp2,
    const float* __restrict__ wg1, const float* __restrict__ wb1,
    const _Float16* __restrict__ W1tG,
    const float* __restrict__ wg2, const float* __restrict__ wb2,
    const _Float16* __restrict__ W2tG,
    float* __restrict__ attn)
{
    __shared__ _Float16 sW1t[128 * 72];
    __shared__ _Float16 sW2t[64 * 136];
    __shared__ _Float16 sscr[8][16 * 136];
    __shared__ float sWp1[48], sPg[16], sPb[16];

    const int t = threadIdx.x;
    const int lane = t & 63;
    const int wv = t >> 6;
    const int col = lane & 15, g = lane >> 4;
    const int q = blockIdx.x * 8 + wv;

    const int jA = knn[q * 16 + col];
    const int4 jC = *(const int4*)(knn + q * 16 + g * 4);
    const int jr[4] = {jC.x, jC.y, jC.z, jC.w};
    const int4 pc = idx4[jA];
    const int4 qc = idx4[q];
    float xqv[4], xkv[4][4], xvv[4][4];
#pragma unroll
    for (int f = 0; f < 4; f++) xqv[f] = xq[q * 64 + f * 16 + col];
#pragma unroll
    for (int r = 0; r < 4; r++)
#pragma unroll
        for (int f = 0; f < 4; f++) {
            xkv[r][f] = xk[jr[r] * 64 + f * 16 + col];
            xvv[r][f] = xv[jr[r] * 64 + f * 16 + col];
        }

    for (int i = t; i < 1024; i += 512) {
        int n = i >> 3, ko = i & 7;
        *(f16x8*)&sW1t[n * 72 + ko * 8] =
            *(const f16x8*)&W1tG[n * 64 + ko * 8];
    }
    for (int i = t; i < 1024; i += 512) {
        int m = i >> 4, ko = i & 15;
        *(f16x8*)&sW2t[m * 136 + ko * 8] =
            *(const f16x8*)&W2tG[m * 128 + ko * 8];
    }
    if (t < 48) sWp1[t] = Wp1[t];
    if (t < 16) { sPg[t] = pg[t] * BN_INV; sPb[t] = pb[t]; }

    float g1c[4], b1c[4], bp2c[4], g2c[8], b2c[8];
#pragma unroll
    for (int f = 0; f < 4; f++) {
        int c = f * 16 + col;
        g1c[f] = wg1[c] * BN_INV; b1c[f] = wb1[c];
        bp2c[f] = bp2[c];
    }
#pragma unroll
    for (int f = 0; f < 8; f++) {
        int o = f * 16 + col;
        g2c[f] = wg2[o] * BN_INV; b2c[f] = wb2[o];
    }
    f16x8 bP[4];
#pragma unroll
    for (int f = 0; f < 4; f++) {
#pragma unroll
        for (int j = 0; j < 8; j++) {
            int h = g * 8 + j;
            bP[f][j] = (g < 2) ? (_Float16)Wp2[h * 64 + f * 16 + col]
                               : (_Float16)0.f;
        }
    }
    __syncthreads();

    _Float16* scr = sscr[wv];

    const float px = (float)(pc.y - qc.y);
    const float py = (float)(pc.z - qc.z);
    const float pz = (float)(pc.w - qc.w);
    f16x8 aph;
#pragma unroll
    for (int j = 0; j < 8; j++) {
        int h = g * 8 + j;
        float v = 0.f;
        if (g < 2) {
            v = px * sWp1[h] + py * sWp1[16 + h] + pz * sWp1[32 + h];
            v = fmaxf(v * sPg[h] + sPb[h], 0.f);
        }
        aph[j] = (_Float16)v;
    }
    f32x4 pr[4];
#pragma unroll
    for (int f = 0; f < 4; f++) {
        f32x4 cini;
#pragma unroll
        for (int r = 0; r < 4; r++) cini[r] = bp2c[f];
        pr[f] = __builtin_amdgcn_mfma_f32_16x16x32_f16(aph, bP[f], cini,
                                                       0, 0, 0);
    }
    f32x4 vvr[4];
#pragma unroll
    for (int r = 0; r < 4; r++) {
#pragma unroll
        for (int f = 0; f < 4; f++) {
            float w0 = xkv[r][f] - xqv[f] + pr[f][r];
            float uu = fmaxf(w0 * g1c[f] + b1c[f], 0.f);
            scr[(g * 4 + r) * 72 + f * 16 + col] = (_Float16)uu;
            vvr[f][r] = xvv[r][f] + pr[f][r];
        }
    }
    f16x8 au[2];
#pragma unroll
    for (int kc = 0; kc < 2; kc++)
        au[kc] = *(const f16x8*)&scr[col * 72 + kc * 32 + g * 8];
    f32x4 acc1[8];
#pragma unroll
    for (int f = 0; f < 8; f++)
#pragma unroll
        for (int r = 0; r < 4; r++) acc1[f][r] = 0.f;
#pragma unroll
    for (int kc = 0; kc < 2; kc++) {
#pragma unroll
        for (int f = 0; f < 8; f++) {
            f16x8 bw = *(const f16x8*)
                &sW1t[(f * 16 + col) * 72 + kc * 32 + g * 8];
            acc1[f] = __builtin_amdgcn_mfma_f32_16x16x32_f16(au[kc], bw,
                                                             acc1[f], 0, 0, 0);
        }
    }
#pragma unroll
    for (int f = 0; f < 8; f++)
#pragma unroll
        for (int r = 0; r < 4; r++) {
            float o1 = fmaxf(acc1[f][r] * g2c[f] + b2c[f], 0.f);
            scr[(g * 4 + r) * 136 + f * 16 + col] = (_Float16)o1;
        }
    f16x8 ao[4];
#pragma unroll
    for (int kc = 0; kc < 4; kc++)
        ao[kc] = *(const f16x8*)&scr[col * 136 + kc * 32 + g * 8];
    f32x4 accL[4];
#pragma unroll
    for (int f = 0; f < 4; f++)
#pragma unroll
        for (int r = 0; r < 4; r++) accL[f][r] = 0.f;
#pragma unroll
    for (int kc = 0; kc < 4; kc++) {
#pragma unroll
        for (int f = 0; f < 4; f++) {
            f16x8 bw = *(const f16x8*)
                &sW2t[(f * 16 + col) * 136 + kc * 32 + g * 8];
            accL[f] = __builtin_amdgcn_mfma_f32_16x16x32_f16(ao[kc], bw,
                                                             accL[f], 0, 0, 0);
        }
    }
    float outv[4];
#pragma unroll
    for (int f = 0; f < 4; f++) {
        float mx = fmaxf(fmaxf(accL[f][0], accL[f][1]),
                         fmaxf(accL[f][2], accL[f][3]));
        mx = fmaxf(mx, __shfl_xor(mx, 16, 64));
        mx = fmaxf(mx, __shfl_xor(mx, 32, 64));
        float sum = 0.f, part = 0.f;
#pragma unroll
        for (int r = 0; r < 4; r++) {
            float e = __expf(accL[f][r] - mx);
            sum += e;
            part = fmaf(e, vvr[f][r], part);
        }
        sum += __shfl_xor(sum, 16, 64);
        sum += __shfl_xor(sum, 32, 64);
        part += __shfl_xor(part, 16, 64);
        part += __shfl_xor(part, 32, 64);
        outv[f] = part / sum;
    }
    float val = (g == 0) ? outv[0]
              : (g == 1) ? outv[1]
              : (g == 2) ? outv[2] : outv[3];
    attn[q * 64 + lane] = val;
}

// ---------------------------------------------------------------------------
// K3: FUSED MFMA-f16 head (R7 structure), weights staged from pre-transposed
// f16 via vector copies.
// ---------------------------------------------------------------------------
__global__ __launch_bounds__(256) void head_kernel(
    const float* __restrict__ feats, const float* __restrict__ attn,
    const _Float16* __restrict__ Wc1tG, const float* __restrict__ cg1,
    const float* __restrict__ cb1, const _Float16* __restrict__ Wc2tG,
    const float* __restrict__ cg2, const float* __restrict__ cb2,
    const _Float16* __restrict__ Wc3tG, const float* __restrict__ bc3,
    const float* __restrict__ lng, const float* __restrict__ lnb,
    float* __restrict__ out)
{
    __shared__ _Float16 sWt[128 * 136];
    __shared__ _Float16 sX[2][16 * 136];
    __shared__ _Float16 sY[2][16 * 136];
    __shared__ float sOut[32 * 68];
    __shared__ float sga[128], sba[128], sgb[128], sbb[128];
    __shared__ float sbc3[64], slng[64], slnb[64];

    const int t = threadIdx.x;
    const int lane = t & 63;
    const int wv = t >> 6;
    const int rg = wv >> 1, hf = wv & 1;
    const int col = lane & 15, g = lane >> 4;
    const int row0 = blockIdx.x * 32;

    {
        int r = t >> 3, c0 = (t & 7) * 16;
        const float* src = (c0 < 64) ? (feats + (row0 + r) * 64 + c0)
                                     : (attn + (row0 + r) * 64 + (c0 - 64));
        _Float16* dst = &sX[r >> 4][(r & 15) * 136 + c0];
#pragma unroll
        for (int i = 0; i < 4; i++) {
            float4 v = ((const float4*)src)[i];
            dst[i * 4 + 0] = (_Float16)v.x;
            dst[i * 4 + 1] = (_Float16)v.y;
            dst[i * 4 + 2] = (_Float16)v.z;
            dst[i * 4 + 3] = (_Float16)v.w;
        }
    }
    auto stageWT = [&](const _Float16* WT, int chunks) {
        for (int i = t; i < chunks; i += 256) {
            int n = i >> 4, ko = i & 15;
            *(f16x8*)&sWt[n * 136 + ko * 8] =
                *(const f16x8*)&WT[n * 128 + ko * 8];
        }
    };
    stageWT(Wc1tG, 2048);
    if (t < 128) {
        sga[t] = cg1[t] * BN_INV; sba[t] = cb1[t];
        sgb[t] = cg2[t] * BN_INV; sbb[t] = cb2[t];
    } else if (t < 192) {
        int o = t - 128;
        sbc3[o] = bc3[o]; slng[o] = lng[o]; slnb[o] = lnb[o];
    }
    __syncthreads();
    {
        f16x8 ax[4];
#pragma unroll
        for (int kc = 0; kc < 4; kc++)
            ax[kc] = *(const f16x8*)&sX[rg][col * 136 + kc * 32 + g * 8];
        f32x4 acc[4];
#pragma unroll
        for (int ft = 0; ft < 4; ft++)
#pragma unroll
            for (int r = 0; r < 4; r++) acc[ft][r] = 0.f;
#pragma unroll
        for (int kc = 0; kc < 4; kc++)
#pragma unroll
            for (int ft = 0; ft < 4; ft++) {
                int n = hf * 64 + ft * 16 + col;
                f16x8 bw = *(const f16x8*)&sWt[n * 136 + kc * 32 + g * 8];
                acc[ft] = __builtin_amdgcn_mfma_f32_16x16x32_f16(ax[kc], bw,
                                                                 acc[ft],
                                                                 0, 0, 0);
            }
#pragma unroll
        for (int ft = 0; ft < 4; ft++)
#pragma unroll
            for (int r = 0; r < 4; r++) {
                int o = hf * 64 + ft * 16 + col;
                float v = fmaxf(acc[ft][r] * sga[o] + sba[o], 0.f);
                sY[rg][(g * 4 + r) * 136 + o] = (_Float16)v;
            }
    }
    __syncthreads();
    stageWT(Wc2tG, 2048);
    __syncthreads();
    {
        f16x8 ax[4];
#pragma unroll
        for (int kc = 0; kc < 4; kc++)
            ax[kc] = *(const f16x8*)&sY[rg][col * 136 + kc * 32 + g * 8];
        f32x4 acc[4];
#pragma unroll
        for (int ft = 0; ft < 4; ft++)
#pragma unroll
            for (int r = 0; r < 4; r++) acc[ft][r] = 0.f;
#pragma unroll
        for (int kc = 0; kc < 4; kc++)
#pragma unroll
            for (int ft = 0; ft < 4; ft++) {
                int n = hf * 64 + ft * 16 + col;
                f16x8 bw = *(const f16x8*)&sWt[n * 136 + kc * 32 + g * 8];
                acc[ft] = __builtin_amdgcn_mfma_f32_16x16x32_f16(ax[kc], bw,
                                                                 acc[ft],
                                                                 0, 0, 0);
            }
#pragma unroll
        for (int ft = 0; ft < 4; ft++)
#pragma unroll
            for (int r = 0; r < 4; r++) {
                int o = hf * 64 + ft * 16 + col;
                float v = fmaxf(acc[ft][r] * sgb[o] + sbb[o], 0.f);
                sX[rg][(g * 4 + r) * 136 + o] = (_Float16)v;
            }
    }
    __syncthreads();
    stageWT(Wc3tG, 1024);
    __syncthreads();
    {
        f16x8 ax[4];
#pragma unroll
        for (int kc = 0; kc < 4; kc++)
            ax[kc] = *(const f16x8*)&sX[rg][col * 136 + kc * 32 + g * 8];
#pragma unroll
        for (int ft = 0; ft < 2; ft++) {
            int n = hf * 32 + ft * 16 + col;
            f32x4 acc;
            float bias = sbc3[n];
#pragma unroll
            for (int r = 0; r < 4; r++) acc[r] = bias;
#pragma unroll
            for (int kc = 0; kc < 4; kc++) {
                f16x8 bw = *(const f16x8*)&sWt[n * 136 + kc * 32 + g * 8];
                acc = __builtin_amdgcn_mfma_f32_16x16x32_f16(ax[kc], bw, acc,
                                                             0, 0, 0);
            }
#pragma unroll
            for (int r = 0; r < 4; r++)
                sOut[(rg * 16 + g * 4 + r) * 68 + n] = acc[r];
        }
    }
    __syncthreads();
    {
        int r = t >> 3, o0 = (t & 7) * 8;
        float v[8];
        float s1 = 0.f, s2 = 0.f;
#pragma unroll
        for (int k = 0; k < 8; k++) {
            v[k] = sOut[r * 68 + o0 + k];
            s1 += v[k];
            s2 = fmaf(v[k], v[k], s2);
        }
#pragma unroll
        for (int d = 1; d < 8; d <<= 1) {
            s1 += __shfl_xor(s1, d, 8);
            s2 += __shfl_xor(s2, d, 8);
        }
        float m = s1 * (1.f / 64.f);
        float var = s2 * (1.f / 64.f) - m * m;
        float inv = 1.f / sqrtf(var + LN_EPS);
        float* dst = out + (row0 + r) * 64;
#pragma unroll
        for (int k = 0; k < 8; k++) {
            int o = o0 + k;
            dst[o] = (v[k] - m) * inv * slng[o] + slnb[o];
        }
    }
}

// ---------------------------------------------------------------------------
extern "C" void kernel_launch(void* const* d_in, const int* in_sizes, int n_in,
                              void* d_out, int out_size, void* d_ws,
                              size_t ws_size, hipStream_t stream)
{
    const int* indices = (const int*)d_in[0];
    const float* feats = (const float*)d_in[1];
    const float* Wq = (const float*)d_in[2];
    const float* bq = (const float*)d_in[3];
    const float* Wk = (const float*)d_in[4];
    const float* bk = (const float*)d_in[5];
    const float* Wv = (const float*)d_in[6];
    const float* bv = (const float*)d_in[7];
    const float* Wp1 = (const float*)d_in[8];
    const float* pg = (const float*)d_in[9];
    const float* pb = (const float*)d_in[10];
    const float* Wp2 = (const float*)d_in[11];
    const float* bp2 = (const float*)d_in[12];
    const float* wg1 = (const float*)d_in[13];
    const float* wb1 = (const float*)d_in[14];
    const float* Ww1 = (const float*)d_in[15];
    const float* wg2 = (const float*)d_in[16];
    const float* wb2 = (const float*)d_in[17];
    const float* Ww2 = (const float*)d_in[18];
    const float* Wc1 = (const float*)d_in[20];
    const float* cg1 = (const float*)d_in[21];
    const float* cb1 = (const float*)d_in[22];
    const float* Wc2 = (const float*)d_in[23];
    const float* cg2 = (const float*)d_in[24];
    const float* cb2 = (const float*)d_in[25];
    const float* Wc3 = (const float*)d_in[26];
    const float* bc3 = (const float*)d_in[27];
    const float* lng = (const float*)d_in[28];
    const float* lnb = (const float*)d_in[29];

    float* out = (float*)d_out;
    float* ws = (float*)d_ws;
    float* xq = ws;
    float* xk = xq + N * C;
    float* xv = xk + N * C;
    float* attn = xv + N * C;
    int* knn = (int*)(attn + N * C);
    _Float16* wt16 = (_Float16*)(knn + N * 16);
    _Float16* W1tG = wt16;              // 128 x 64
    _Float16* W2tG = W1tG + 8192;       // 64 x 128
    _Float16* Wc1tG = W2tG + 8192;      // 128 x 128
    _Float16* Wc2tG = Wc1tG + 16384;    // 128 x 128
    _Float16* Wc3tG = Wc2tG + 16384;    // 64 x 128

    qkv_knn_kernel<<<1089, 512, 32768, stream>>>(
        (const int4*)indices, knn, feats, Wq, bq, Wk, bk, Wv, bv, xq, xk, xv,
        Ww1, Ww2, Wc1, Wc2, Wc3, W1tG, W2tG, Wc1tG, Wc2tG, Wc3tG);
    attn_kernel<<<1024, 512, 0, stream>>>(
        (const int4*)indices, knn, xq, xk, xv, Wp1, pg, pb, Wp2, bp2, wg1,
        wb1, W1tG, wg2, wb2, W2tG, attn);
    head_kernel<<<256, 256, 0, stream>>>(feats, attn, Wc1tG, cg1, cb1, Wc2tG,
                                         cg2, cb2, Wc3tG, bc3, lng, lnb, out);
}

// Round 12
// 198.960 us; speedup vs baseline: 1.3219x; 1.0040x over previous
//
#include <hip/hip_runtime.h>

#define N 8192
#define C 64
#define S 16

static constexpr float BN_INV = 0.9999950000374997f; // 1/sqrt(1+1e-5)
static constexpr float LN_EPS = 1e-5f;

typedef _Float16 f16x8 __attribute__((ext_vector_type(8)));
typedef float f32x4 __attribute__((ext_vector_type(4)));

__device__ __forceinline__ void sort2(unsigned& x, unsigned& y)
{
    unsigned lo = min(x, y);
    unsigned hi = max(x, y);
    x = lo;
    y = hi;
}

__device__ __forceinline__ unsigned med3u(unsigned a, unsigned b, unsigned c)
{
    unsigned r;
    asm("v_med3_u32 %0, %1, %2, %3" : "=v"(r) : "v"(a), "v"(b), "v"(c));
    return r;
}

// insert k into sorted a0<=a1<=a2<=a3, keeping the 4 smallest (5 VALU ops)
__device__ __forceinline__ void insert4(unsigned& a0, unsigned& a1,
                                        unsigned& a2, unsigned& a3,
                                        unsigned k)
{
    unsigned m = min(a3, k);
    unsigned n1 = med3u(a0, a1, m);
    unsigned n2 = med3u(a1, a2, m);
    a3 = max(a2, m);
    a0 = min(a0, m);
    a1 = n1;
    a2 = n2;
}

__device__ __forceinline__ int mbcnt64(unsigned long long m)
{
    int lo = __builtin_amdgcn_mbcnt_lo((unsigned)m, 0);
    return __builtin_amdgcn_mbcnt_hi((unsigned)(m >> 32), lo);
}

// ---------------------------------------------------------------------------
// K1: FUSED knn + qkv + weight-prep. Blocks [0,1024): exact 16-NN set
// (order-free: attn is permutation-invariant over neighbors). Scan reads 4
// packed candidates per ds_read_b128; two top-4 chains per lane with 5-op
// med3 inserts; radix-select 16th-smallest + ballot/mbcnt compaction;
// exact fallback if any lane may have dropped a key < T.
// Blocks [1024,1088): MFMA-f16 qkv. Block 1088: f16 weight transposes.
// ---------------------------------------------------------------------------
__global__ __launch_bounds__(512) void qkv_knn_kernel(
    const int4* __restrict__ idx4, int* __restrict__ knn_out,
    const float* __restrict__ feats,
    const float* __restrict__ Wq, const float* __restrict__ bq,
    const float* __restrict__ Wk, const float* __restrict__ bk,
    const float* __restrict__ Wv, const float* __restrict__ bv,
    float* __restrict__ xq, float* __restrict__ xk, float* __restrict__ xv,
    const float* __restrict__ Ww1, const float* __restrict__ Ww2,
    const float* __restrict__ Wc1, const float* __restrict__ Wc2,
    const float* __restrict__ Wc3,
    _Float16* __restrict__ W1tG, _Float16* __restrict__ W2tG,
    _Float16* __restrict__ Wc1tG, _Float16* __restrict__ Wc2tG,
    _Float16* __restrict__ Wc3tG)
{
    extern __shared__ char smem[];
    const int t = threadIdx.x;
    const int lane = t & 63;
    const int wv = t >> 6;
    if (blockIdx.x < 1024) {
        unsigned* pk = (unsigned*)smem;
        const int q = blockIdx.x * 8 + wv;
#pragma unroll
        for (int i = 0; i < 16; i++) {
            int j = i * 512 + t;
            int4 c = idx4[j];
            pk[j] = (unsigned)c.y | ((unsigned)c.z << 8) |
                    ((unsigned)c.w << 16);
        }
        const int4 qc = idx4[q];
        const int qx = qc.y, qy = qc.z, qz = qc.w;
        const unsigned qq = (unsigned)(qx * qx + qy * qy + qz * qz);
#if __has_builtin(__builtin_amdgcn_udot4)
        const unsigned qpk2 = (unsigned)(2 * qx) | ((unsigned)(2 * qy) << 8) |
                              ((unsigned)(2 * qz) << 16);
#endif
        unsigned a0 = 0xFFFFFFFFu, a1 = 0xFFFFFFFFu, a2 = 0xFFFFFFFFu,
                 a3 = 0xFFFFFFFFu;
        unsigned b0 = 0xFFFFFFFFu, b1 = 0xFFFFFFFFu, b2 = 0xFFFFFFFFu,
                 b3 = 0xFFFFFFFFu;
        __syncthreads();
        const uint4* pk4 = (const uint4*)pk;
#pragma unroll 4
        for (int i = 0; i < 32; ++i) {
            uint4 cd = pk4[i * 64 + lane];
            const unsigned j0 = (unsigned)((i * 64 + lane) * 4);
#if __has_builtin(__builtin_amdgcn_udot4)
            unsigned d20 = __builtin_amdgcn_udot4(cd.x, cd.x, qq, false) -
                           __builtin_amdgcn_udot4(cd.x, qpk2, 0u, false);
            unsigned d21 = __builtin_amdgcn_udot4(cd.y, cd.y, qq, false) -
                           __builtin_amdgcn_udot4(cd.y, qpk2, 0u, false);
            unsigned d22 = __builtin_amdgcn_udot4(cd.z, cd.z, qq, false) -
                           __builtin_amdgcn_udot4(cd.z, qpk2, 0u, false);
            unsigned d23 = __builtin_amdgcn_udot4(cd.w, cd.w, qq, false) -
                           __builtin_amdgcn_udot4(cd.w, qpk2, 0u, false);
#else
            unsigned d20, d21, d22, d23;
            {
                unsigned ps[4] = {cd.x, cd.y, cd.z, cd.w};
                unsigned ds[4];
#pragma unroll
                for (int c = 0; c < 4; c++) {
                    int x = (int)(ps[c] & 255u), y = (int)((ps[c] >> 8) & 255u),
                        z = (int)(ps[c] >> 16);
                    int dx = x - qx, dy = y - qy, dz = z - qz;
                    ds[c] = (unsigned)(dx * dx + dy * dy + dz * dz);
                }
                d20 = ds[0]; d21 = ds[1]; d22 = ds[2]; d23 = ds[3];
            }
#endif
            insert4(a0, a1, a2, a3, (d20 << 13) + j0);
            insert4(a0, a1, a2, a3, (d21 << 13) + j0 + 1);
            insert4(b0, b1, b2, b3, (d22 << 13) + j0 + 2);
            insert4(b0, b1, b2, b3, (d23 << 13) + j0 + 3);
        }
        // smallest 4 of the two sorted-4 lists
        unsigned t0 = min(a0, b3), t1 = min(a1, b2), t2 = min(a2, b1),
                 t3 = min(a3, b0);
        sort2(t0, t2); sort2(t1, t3); sort2(t0, t1); sort2(t2, t3);
        sort2(t1, t2);
        // radix-select T = 16th smallest of the 256 kept keys (keys < 2^29)
        unsigned prefix = 0u;
#pragma unroll
        for (int bit = 28; bit >= 0; --bit) {
            unsigned cand = prefix | (1u << bit);
            int c = __popcll(__ballot(t0 < cand)) +
                    __popcll(__ballot(t1 < cand)) +
                    __popcll(__ballot(t2 < cand)) +
                    __popcll(__ballot(t3 < cand));
            if (c < 16) prefix = cand;
        }
        const unsigned T = prefix;
        // compaction write of the 16 keys <= T (unordered — see header)
        {
            unsigned long long m0 = __ballot(t0 <= T);
            unsigned long long m1 = __ballot(t1 <= T);
            unsigned long long m2 = __ballot(t2 <= T);
            unsigned long long m3 = __ballot(t3 <= T);
            int base1 = __popcll(m0);
            int base2 = base1 + __popcll(m1);
            int base3 = base2 + __popcll(m2);
            int* dst = knn_out + q * 16;
            if (t0 <= T) dst[mbcnt64(m0)] = (int)(t0 & 8191u);
            if (t1 <= T) dst[base1 + mbcnt64(m1)] = (int)(t1 & 8191u);
            if (t2 <= T) dst[base2 + mbcnt64(m2)] = (int)(t2 & 8191u);
            if (t3 <= T) dst[base3 + mbcnt64(m3)] = (int)(t3 & 8191u);
        }
        // exactness: bad iff some lane may have dropped a key < T
        unsigned long long bad = __ballot(t3 < T);
        if (bad) {
            unsigned c0 = 0xFFFFFFFFu, c1 = 0xFFFFFFFFu, c2 = 0xFFFFFFFFu,
                     c3 = 0xFFFFFFFFu, c4 = 0xFFFFFFFFu, c5 = 0xFFFFFFFFu,
                     c6 = 0xFFFFFFFFu, c7 = 0xFFFFFFFFu, c8 = 0xFFFFFFFFu,
                     c9 = 0xFFFFFFFFu, c10 = 0xFFFFFFFFu, c11 = 0xFFFFFFFFu,
                     c12 = 0xFFFFFFFFu, c13 = 0xFFFFFFFFu, c14 = 0xFFFFFFFFu,
                     c15 = 0xFFFFFFFFu;
            for (int i = 0; i < 128; ++i) {
                int j = i * 64 + lane;
                int4 cd = idx4[j];
                int dx = cd.y - qx, dy = cd.z - qy, dz = cd.w - qz;
                unsigned d2 = (unsigned)(dx * dx + dy * dy + dz * dz);
                unsigned key = (d2 << 13) + (unsigned)j;
                c15 = min(c15, key);
                sort2(c14, c15); sort2(c13, c14); sort2(c12, c13);
                sort2(c11, c12); sort2(c10, c11); sort2(c9, c10);
                sort2(c8, c9);   sort2(c7, c8);   sort2(c6, c7);
                sort2(c5, c6);   sort2(c4, c5);   sort2(c3, c4);
                sort2(c2, c3);   sort2(c1, c2);   sort2(c0, c1);
            }
            for (int r = 0; r < 16; ++r) {
                unsigned m = c0;
                m = min(m, (unsigned)__shfl_xor((int)m, 1, 64));
                m = min(m, (unsigned)__shfl_xor((int)m, 2, 64));
                m = min(m, (unsigned)__shfl_xor((int)m, 4, 64));
                m = min(m, (unsigned)__shfl_xor((int)m, 8, 64));
                m = min(m, (unsigned)__shfl_xor((int)m, 16, 64));
                m = min(m, (unsigned)__shfl_xor((int)m, 32, 64));
                if (lane == r) knn_out[q * 16 + r] = (int)(m & 8191u);
                bool win = (c0 == m);
                c0 = win ? c1 : c0;    c1 = win ? c2 : c1;
                c2 = win ? c3 : c2;    c3 = win ? c4 : c3;
                c4 = win ? c5 : c4;    c5 = win ? c6 : c5;
                c6 = win ? c7 : c6;    c7 = win ? c8 : c7;
                c8 = win ? c9 : c8;    c9 = win ? c10 : c9;
                c10 = win ? c11 : c10; c11 = win ? c12 : c11;
                c12 = win ? c13 : c12; c13 = win ? c14 : c13;
                c14 = win ? c15 : c14; c15 = win ? 0xFFFFFFFFu : c15;
            }
        }
    } else if (blockIdx.x < 1088) {
        _Float16* sBt = (_Float16*)smem;
        float* sbias = (float*)(smem + 192 * 72 * 2);
        const int col = lane & 15, g = lane >> 4;
        const int bid2 = blockIdx.x - 1024;
        const int row0w = bid2 * 128 + wv * 16;
        {
            const float* Ws[3] = {Wq, Wk, Wv};
#pragma unroll
            for (int m = 0; m < 3; m++) {
                int k = t >> 3, nb = (t & 7) * 8;
                const float4* src = (const float4*)(Ws[m] + k * 64 + nb);
                float4 w0 = src[0], w1 = src[1];
                _Float16* dst = &sBt[(m * 64 + nb) * 72 + k];
                dst[0 * 72] = (_Float16)w0.x; dst[1 * 72] = (_Float16)w0.y;
                dst[2 * 72] = (_Float16)w0.z; dst[3 * 72] = (_Float16)w0.w;
                dst[4 * 72] = (_Float16)w1.x; dst[5 * 72] = (_Float16)w1.y;
                dst[6 * 72] = (_Float16)w1.z; dst[7 * 72] = (_Float16)w1.w;
            }
            if (t < 64) sbias[t] = bq[t];
            else if (t < 128) sbias[t] = bk[t - 64];
            else if (t < 192) sbias[t] = bv[t - 128];
        }
        __syncthreads();
        f16x8 au[2];
#pragma unroll
        for (int kc = 0; kc < 2; kc++) {
            const float4* src = (const float4*)
                (feats + (row0w + col) * 64 + kc * 32 + g * 8);
            float4 v0 = src[0], v1 = src[1];
            au[kc][0] = (_Float16)v0.x; au[kc][1] = (_Float16)v0.y;
            au[kc][2] = (_Float16)v0.z; au[kc][3] = (_Float16)v0.w;
            au[kc][4] = (_Float16)v1.x; au[kc][5] = (_Float16)v1.y;
            au[kc][6] = (_Float16)v1.z; au[kc][7] = (_Float16)v1.w;
        }
        float* outs[3] = {xq, xk, xv};
#pragma unroll
        for (int f = 0; f < 12; f++) {
            f32x4 acc;
            float bias = sbias[f * 16 + col];
#pragma unroll
            for (int r = 0; r < 4; r++) acc[r] = bias;
#pragma unroll
            for (int kc = 0; kc < 2; kc++) {
                f16x8 bw = *(const f16x8*)
                    &sBt[(f * 16 + col) * 72 + kc * 32 + g * 8];
                acc = __builtin_amdgcn_mfma_f32_16x16x32_f16(au[kc], bw, acc,
                                                             0, 0, 0);
            }
            float* o = outs[f >> 2];
            int cg = (f & 3) * 16 + col;
#pragma unroll
            for (int r = 0; r < 4; r++)
                o[(row0w + g * 4 + r) * 64 + cg] = acc[r];
        }
    } else {
        // weight prep: WT[n][k] (k-contiguous) = W[k][n], f16
        for (int o = t; o < 8192; o += 512) {         // Ww1: 64x128
            int n = o >> 6, k = o & 63;
            W1tG[o] = (_Float16)Ww1[k * 128 + n];
        }
        for (int o = t; o < 8192; o += 512) {         // Ww2: 128x64
            int n = o >> 7, k = o & 127;
            W2tG[o] = (_Float16)Ww2[k * 64 + n];
        }
        for (int o = t; o < 16384; o += 512) {        // Wc1: 128x128
            int n = o >> 7, k = o & 127;
            Wc1tG[o] = (_Float16)Wc1[k * 128 + n];
        }
        for (int o = t; o < 16384; o += 512) {        // Wc2: 128x128
            int n = o >> 7, k = o & 127;
            Wc2tG[o] = (_Float16)Wc2[k * 128 + n];
        }
        for (int o = t; o < 8192; o += 512) {         // Wc3: 128x64
            int n = o >> 7, k = o & 127;
            Wc3tG[o] = (_Float16)Wc3[k * 64 + n];
        }
    }
}

// ---------------------------------------------------------------------------
// K2: MFMA vector-attention (R7/R11 structure; best known). 1024 x 512; one
// query per wave. bw2 dropped (cancels in softmax over s).
// ---------------------------------------------------------------------------
__global__ __launch_bounds__(512, 4) void attn_kernel(
    const int4* __restrict__ idx4, const int* __restrict__ knn,
    const float* __restrict__ xq, const float* __restrict__ xk,
    const float* __restrict__ xv,
    const float* __restrict__ Wp1, const float* __restrict__ pg,
    const float* __restrict__ pb, const float* __restrict__ Wp2,
    const float* __restrict__ bp2,
    const float* __restrict__ wg1, const float* __restrict__ wb1,
    const _Float16* __restrict__ W1tG,
    const float* __restrict__ wg2, const float* __restrict__ wb2,
    const _Float16* __restrict__ W2tG,
    float* __restrict__ attn)
{
    __shared__ _Float16 sW1t[128 * 72];
    __shared__ _Float16 sW2t[64 * 136];
    __shared__ _Float16 sscr[8][16 * 136];
    __shared__ float sWp1[48], sPg[16], sPb[16];

    const int t = threadIdx.x;
    const int lane = t & 63;
    const int wv = t >> 6;
    const int col = lane & 15, g = lane >> 4;
    const int q = blockIdx.x * 8 + wv;

    const int jA = knn[q * 16 + col];
    const int4 jC = *(const int4*)(knn + q * 16 + g * 4);
    const int jr[4] = {jC.x, jC.y, jC.z, jC.w};
    const int4 pc = idx4[jA];
    const int4 qc = idx4[q];
    float xqv[4], xkv[4][4], xvv[4][4];
#pragma unroll
    for (int f = 0; f < 4; f++) xqv[f] = xq[q * 64 + f * 16 + col];
#pragma unroll
    for (int r = 0; r < 4; r++)
#pragma unroll
        for (int f = 0; f < 4; f++) {
            xkv[r][f] = xk[jr[r] * 64 + f * 16 + col];
            xvv[r][f] = xv[jr[r] * 64 + f * 16 + col];
        }

    for (int i = t; i < 1024; i += 512) {
        int n = i >> 3, ko = i & 7;
        *(f16x8*)&sW1t[n * 72 + ko * 8] =
            *(const f16x8*)&W1tG[n * 64 + ko * 8];
    }
    for (int i = t; i < 1024; i += 512) {
        int m = i >> 4, ko = i & 15;
        *(f16x8*)&sW2t[m * 136 + ko * 8] =
            *(const f16x8*)&W2tG[m * 128 + ko * 8];
    }
    if (t < 48) sWp1[t] = Wp1[t];
    if (t < 16) { sPg[t] = pg[t] * BN_INV; sPb[t] = pb[t]; }

    float g1c[4], b1c[4], bp2c[4], g2c[8], b2c[8];
#pragma unroll
    for (int f = 0; f < 4; f++) {
        int c = f * 16 + col;
        g1c[f] = wg1[c] * BN_INV; b1c[f] = wb1[c];
        bp2c[f] = bp2[c];
    }
#pragma unroll
    for (int f = 0; f < 8; f++) {
        int o = f * 16 + col;
        g2c[f] = wg2[o] * BN_INV; b2c[f] = wb2[o];
    }
    f16x8 bP[4];
#pragma unroll
    for (int f = 0; f < 4; f++) {
#pragma unroll
        for (int j = 0; j < 8; j++) {
            int h = g * 8 + j;
            bP[f][j] = (g < 2) ? (_Float16)Wp2[h * 64 + f * 16 + col]
                               : (_Float16)0.f;
        }
    }
    __syncthreads();

    _Float16* scr = sscr[wv];

    const float px = (float)(pc.y - qc.y);
    const float py = (float)(pc.z - qc.z);
    const float pz = (float)(pc.w - qc.w);
    f16x8 aph;
#pragma unroll
    for (int j = 0; j < 8; j++) {
        int h = g * 8 + j;
        float v = 0.f;
        if (g < 2) {
            v = px * sWp1[h] + py * sWp1[16 + h] + pz * sWp1[32 + h];
            v = fmaxf(v * sPg[h] + sPb[h], 0.f);
        }
        aph[j] = (_Float16)v;
    }
    f32x4 pr[4];
#pragma unroll
    for (int f = 0; f < 4; f++) {
        f32x4 cini;
#pragma unroll
        for (int r = 0; r < 4; r++) cini[r] = bp2c[f];
        pr[f] = __builtin_amdgcn_mfma_f32_16x16x32_f16(aph, bP[f], cini,
                                                       0, 0, 0);
    }
    f32x4 vvr[4];
#pragma unroll
    for (int r = 0; r < 4; r++) {
#pragma unroll
        for (int f = 0; f < 4; f++) {
            float w0 = xkv[r][f] - xqv[f] + pr[f][r];
            float uu = fmaxf(w0 * g1c[f] + b1c[f], 0.f);
            scr[(g * 4 + r) * 72 + f * 16 + col] = (_Float16)uu;
            vvr[f][r] = xvv[r][f] + pr[f][r];
        }
    }
    f16x8 au[2];
#pragma unroll
    for (int kc = 0; kc < 2; kc++)
        au[kc] = *(const f16x8*)&scr[col * 72 + kc * 32 + g * 8];
    f32x4 acc1[8];
#pragma unroll
    for (int f = 0; f < 8; f++)
#pragma unroll
        for (int r = 0; r < 4; r++) acc1[f][r] = 0.f;
#pragma unroll
    for (int kc = 0; kc < 2; kc++) {
#pragma unroll
        for (int f = 0; f < 8; f++) {
            f16x8 bw = *(const f16x8*)
                &sW1t[(f * 16 + col) * 72 + kc * 32 + g * 8];
            acc1[f] = __builtin_amdgcn_mfma_f32_16x16x32_f16(au[kc], bw,
                                                             acc1[f], 0, 0, 0);
        }
    }
#pragma unroll
    for (int f = 0; f < 8; f++)
#pragma unroll
        for (int r = 0; r < 4; r++) {
            float o1 = fmaxf(acc1[f][r] * g2c[f] + b2c[f], 0.f);
            scr[(g * 4 + r) * 136 + f * 16 + col] = (_Float16)o1;
        }
    f16x8 ao[4];
#pragma unroll
    for (int kc = 0; kc < 4; kc++)
        ao[kc] = *(const f16x8*)&scr[col * 136 + kc * 32 + g * 8];
    f32x4 accL[4];
#pragma unroll
    for (int f = 0; f < 4; f++)
#pragma unroll
        for (int r = 0; r < 4; r++) accL[f][r] = 0.f;
#pragma unroll
    for (int kc = 0; kc < 4; kc++) {
#pragma unroll
        for (int f = 0; f < 4; f++) {
            f16x8 bw = *(const f16x8*)
                &sW2t[(f * 16 + col) * 136 + kc * 32 + g * 8];
            accL[f] = __builtin_amdgcn_mfma_f32_16x16x32_f16(ao[kc], bw,
                                                             accL[f], 0, 0, 0);
        }
    }
    float outv[4];
#pragma unroll
    for (int f = 0; f < 4; f++) {
        float mx = fmaxf(fmaxf(accL[f][0], accL[f][1]),
                         fmaxf(accL[f][2], accL[f][3]));
        mx = fmaxf(mx, __shfl_xor(mx, 16, 64));
        mx = fmaxf(mx, __shfl_xor(mx, 32, 64));
        float sum = 0.f, part = 0.f;
#pragma unroll
        for (int r = 0; r < 4; r++) {
            float e = __expf(accL[f][r] - mx);
            sum += e;
            part = fmaf(e, vvr[f][r], part);
        }
        sum += __shfl_xor(sum, 16, 64);
        sum += __shfl_xor(sum, 32, 64);
        part += __shfl_xor(part, 16, 64);
        part += __shfl_xor(part, 32, 64);
        outv[f] = part / sum;
    }
    float val = (g == 0) ? outv[0]
              : (g == 1) ? outv[1]
              : (g == 2) ? outv[2] : outv[3];
    attn[q * 64 + lane] = val;
}

// ---------------------------------------------------------------------------
// K3: FUSED MFMA-f16 head (R7 structure), weights staged from pre-transposed
// f16 via vector copies.
// ---------------------------------------------------------------------------
__global__ __launch_bounds__(256) void head_kernel(
    const float* __restrict__ feats, const float* __restrict__ attn,
    const _Float16* __restrict__ Wc1tG, const float* __restrict__ cg1,
    const float* __restrict__ cb1, const _Float16* __restrict__ Wc2tG,
    const float* __restrict__ cg2, const float* __restrict__ cb2,
    const _Float16* __restrict__ Wc3tG, const float* __restrict__ bc3,
    const float* __restrict__ lng, const float* __restrict__ lnb,
    float* __restrict__ out)
{
    __shared__ _Float16 sWt[128 * 136];
    __shared__ _Float16 sX[2][16 * 136];
    __shared__ _Float16 sY[2][16 * 136];
    __shared__ float sOut[32 * 68];
    __shared__ float sga[128], sba[128], sgb[128], sbb[128];
    __shared__ float sbc3[64], slng[64], slnb[64];

    const int t = threadIdx.x;
    const int lane = t & 63;
    const int wv = t >> 6;
    const int rg = wv >> 1, hf = wv & 1;
    const int col = lane & 15, g = lane >> 4;
    const int row0 = blockIdx.x * 32;

    {
        int r = t >> 3, c0 = (t & 7) * 16;
        const float* src = (c0 < 64) ? (feats + (row0 + r) * 64 + c0)
                                     : (attn + (row0 + r) * 64 + (c0 - 64));
        _Float16* dst = &sX[r >> 4][(r & 15) * 136 + c0];
#pragma unroll
        for (int i = 0; i < 4; i++) {
            float4 v = ((const float4*)src)[i];
            dst[i * 4 + 0] = (_Float16)v.x;
            dst[i * 4 + 1] = (_Float16)v.y;
            dst[i * 4 + 2] = (_Float16)v.z;
            dst[i * 4 + 3] = (_Float16)v.w;
        }
    }
    auto stageWT = [&](const _Float16* WT, int chunks) {
        for (int i = t; i < chunks; i += 256) {
            int n = i >> 4, ko = i & 15;
            *(f16x8*)&sWt[n * 136 + ko * 8] =
                *(const f16x8*)&WT[n * 128 + ko * 8];
        }
    };
    stageWT(Wc1tG, 2048);
    if (t < 128) {
        sga[t] = cg1[t] * BN_INV; sba[t] = cb1[t];
        sgb[t] = cg2[t] * BN_INV; sbb[t] = cb2[t];
    } else if (t < 192) {
        int o = t - 128;
        sbc3[o] = bc3[o]; slng[o] = lng[o]; slnb[o] = lnb[o];
    }
    __syncthreads();
    {
        f16x8 ax[4];
#pragma unroll
        for (int kc = 0; kc < 4; kc++)
            ax[kc] = *(const f16x8*)&sX[rg][col * 136 + kc * 32 + g * 8];
        f32x4 acc[4];
#pragma unroll
        for (int ft = 0; ft < 4; ft++)
#pragma unroll
            for (int r = 0; r < 4; r++) acc[ft][r] = 0.f;
#pragma unroll
        for (int kc = 0; kc < 4; kc++)
#pragma unroll
            for (int ft = 0; ft < 4; ft++) {
                int n = hf * 64 + ft * 16 + col;
                f16x8 bw = *(const f16x8*)&sWt[n * 136 + kc * 32 + g * 8];
                acc[ft] = __builtin_amdgcn_mfma_f32_16x16x32_f16(ax[kc], bw,
                                                                 acc[ft],
                                                                 0, 0, 0);
            }
#pragma unroll
        for (int ft = 0; ft < 4; ft++)
#pragma unroll
            for (int r = 0; r < 4; r++) {
                int o = hf * 64 + ft * 16 + col;
                float v = fmaxf(acc[ft][r] * sga[o] + sba[o], 0.f);
                sY[rg][(g * 4 + r) * 136 + o] = (_Float16)v;
            }
    }
    __syncthreads();
    stageWT(Wc2tG, 2048);
    __syncthreads();
    {
        f16x8 ax[4];
#pragma unroll
        for (int kc = 0; kc < 4; kc++)
            ax[kc] = *(const f16x8*)&sY[rg][col * 136 + kc * 32 + g * 8];
        f32x4 acc[4];
#pragma unroll
        for (int ft = 0; ft < 4; ft++)
#pragma unroll
            for (int r = 0; r < 4; r++) acc[ft][r] = 0.f;
#pragma unroll
        for (int kc = 0; kc < 4; kc++)
#pragma unroll
            for (int ft = 0; ft < 4; ft++) {
                int n = hf * 64 + ft * 16 + col;
                f16x8 bw = *(const f16x8*)&sWt[n * 136 + kc * 32 + g * 8];
                acc[ft] = __builtin_amdgcn_mfma_f32_16x16x32_f16(ax[kc], bw,
                                                                 acc[ft],
                                                                 0, 0, 0);
            }
#pragma unroll
        for (int ft = 0; ft < 4; ft++)
#pragma unroll
            for (int r = 0; r < 4; r++) {
                int o = hf * 64 + ft * 16 + col;
                float v = fmaxf(acc[ft][r] * sgb[o] + sbb[o], 0.f);
                sX[rg][(g * 4 + r) * 136 + o] = (_Float16)v;
            }
    }
    __syncthreads();
    stageWT(Wc3tG, 1024);
    __syncthreads();
    {
        f16x8 ax[4];
#pragma unroll
        for (int kc = 0; kc < 4; kc++)
            ax[kc] = *(const f16x8*)&sX[rg][col * 136 + kc * 32 + g * 8];
#pragma unroll
        for (int ft = 0; ft < 2; ft++) {
            int n = hf * 32 + ft * 16 + col;
            f32x4 acc;
            float bias = sbc3[n];
#pragma unroll
            for (int r = 0; r < 4; r++) acc[r] = bias;
#pragma unroll
            for (int kc = 0; kc < 4; kc++) {
                f16x8 bw = *(const f16x8*)&sWt[n * 136 + kc * 32 + g * 8];
                acc = __builtin_amdgcn_mfma_f32_16x16x32_f16(ax[kc], bw, acc,
                                                             0, 0, 0);
            }
#pragma unroll
            for (int r = 0; r < 4; r++)
                sOut[(rg * 16 + g * 4 + r) * 68 + n] = acc[r];
        }
    }
    __syncthreads();
    {
        int r = t >> 3, o0 = (t & 7) * 8;
        float v[8];
        float s1 = 0.f, s2 = 0.f;
#pragma unroll
        for (int k = 0; k < 8; k++) {
            v[k] = sOut[r * 68 + o0 + k];
            s1 += v[k];
            s2 = fmaf(v[k], v[k], s2);
        }
#pragma unroll
        for (int d = 1; d < 8; d <<= 1) {
            s1 += __shfl_xor(s1, d, 8);
            s2 += __shfl_xor(s2, d, 8);
        }
        float m = s1 * (1.f / 64.f);
        float var = s2 * (1.f / 64.f) - m * m;
        float inv = 1.f / sqrtf(var + LN_EPS);
        float* dst = out + (row0 + r) * 64;
#pragma unroll
        for (int k = 0; k < 8; k++) {
            int o = o0 + k;
            dst[o] = (v[k] - m) * inv * slng[o] + slnb[o];
        }
    }
}

// ---------------------------------------------------------------------------
extern "C" void kernel_launch(void* const* d_in, const int* in_sizes, int n_in,
                              void* d_out, int out_size, void* d_ws,
                              size_t ws_size, hipStream_t stream)
{
    const int* indices = (const int*)d_in[0];
    const float* feats = (const float*)d_in[1];
    const float* Wq = (const float*)d_in[2];
    const float* bq = (const float*)d_in[3];
    const float* Wk = (const float*)d_in[4];
    const float* bk = (const float*)d_in[5];
    const float* Wv = (const float*)d_in[6];
    const float* bv = (const float*)d_in[7];
    const float* Wp1 = (const float*)d_in[8];
    const float* pg = (const float*)d_in[9];
    const float* pb = (const float*)d_in[10];
    const float* Wp2 = (const float*)d_in[11];
    const float* bp2 = (const float*)d_in[12];
    const float* wg1 = (const float*)d_in[13];
    const float* wb1 = (const float*)d_in[14];
    const float* Ww1 = (const float*)d_in[15];
    const float* wg2 = (const float*)d_in[16];
    const float* wb2 = (const float*)d_in[17];
    const float* Ww2 = (const float*)d_in[18];
    const float* Wc1 = (const float*)d_in[20];
    const float* cg1 = (const float*)d_in[21];
    const float* cb1 = (const float*)d_in[22];
    const float* Wc2 = (const float*)d_in[23];
    const float* cg2 = (const float*)d_in[24];
    const float* cb2 = (const float*)d_in[25];
    const float* Wc3 = (const float*)d_in[26];
    const float* bc3 = (const float*)d_in[27];
    const float* lng = (const float*)d_in[28];
    const float* lnb = (const float*)d_in[29];

    float* out = (float*)d_out;
    float* ws = (float*)d_ws;
    float* xq = ws;
    float* xk = xq + N * C;
    float* xv = xk + N * C;
    float* attn = xv + N * C;
    int* knn = (int*)(attn + N * C);
    _Float16* wt16 = (_Float16*)(knn + N * 16);
    _Float16* W1tG = wt16;              // 128 x 64
    _Float16* W2tG = W1tG + 8192;       // 64 x 128
    _Float16* Wc1tG = W2tG + 8192;      // 128 x 128
    _Float16* Wc2tG = Wc1tG + 16384;    // 128 x 128
    _Float16* Wc3tG = Wc2tG + 16384;    // 64 x 128

    qkv_knn_kernel<<<1089, 512, 32768, stream>>>(
        (const int4*)indices, knn, feats, Wq, bq, Wk, bk, Wv, bv, xq, xk, xv,
        Ww1, Ww2, Wc1, Wc2, Wc3, W1tG, W2tG, Wc1tG, Wc2tG, Wc3tG);
    attn_kernel<<<1024, 512, 0, stream>>>(
        (const int4*)indices, knn, xq, xk, xv, Wp1, pg, pb, Wp2, bp2, wg1,
        wb1, W1tG, wg2, wb2, W2tG, attn);
    head_kernel<<<256, 256, 0, stream>>>(feats, attn, Wc1tG, cg1, cb1, Wc2tG,
                                         cg2, cb2, Wc3tG, bc3, lng, lnb, out);
}

// Round 13
// 189.567 us; speedup vs baseline: 1.3874x; 1.0496x over previous
//
#include <hip/hip_runtime.h>

#define N 8192
#define C 64
#define S 16

static constexpr float BN_INV = 0.9999950000374997f; // 1/sqrt(1+1e-5)
static constexpr float LN_EPS = 1e-5f;

typedef _Float16 f16x8 __attribute__((ext_vector_type(8)));
typedef _Float16 f16x4 __attribute__((ext_vector_type(4)));
typedef float f32x4 __attribute__((ext_vector_type(4)));

__device__ __forceinline__ void sort2(unsigned& x, unsigned& y)
{
    unsigned lo = min(x, y);
    unsigned hi = max(x, y);
    x = lo;
    y = hi;
}

__device__ __forceinline__ unsigned med3u(unsigned a, unsigned b, unsigned c)
{
    unsigned r;
    asm("v_med3_u32 %0, %1, %2, %3" : "=v"(r) : "v"(a), "v"(b), "v"(c));
    return r;
}

__device__ __forceinline__ void insert4(unsigned& a0, unsigned& a1,
                                        unsigned& a2, unsigned& a3,
                                        unsigned k)
{
    unsigned m = min(a3, k);
    unsigned n1 = med3u(a0, a1, m);
    unsigned n2 = med3u(a1, a2, m);
    a3 = max(a2, m);
    a0 = min(a0, m);
    a1 = n1;
    a2 = n2;
}

__device__ __forceinline__ int mbcnt64(unsigned long long m)
{
    int lo = __builtin_amdgcn_mbcnt_lo((unsigned)m, 0);
    return __builtin_amdgcn_mbcnt_hi((unsigned)(m >> 32), lo);
}

// ---------------------------------------------------------------------------
// K1: FUSED knn + qkv + weight-prep (verbatim R12 — protected baseline).
// ---------------------------------------------------------------------------
__global__ __launch_bounds__(512) void qkv_knn_kernel(
    const int4* __restrict__ idx4, int* __restrict__ knn_out,
    const float* __restrict__ feats,
    const float* __restrict__ Wq, const float* __restrict__ bq,
    const float* __restrict__ Wk, const float* __restrict__ bk,
    const float* __restrict__ Wv, const float* __restrict__ bv,
    float* __restrict__ xq, float* __restrict__ xk, float* __restrict__ xv,
    const float* __restrict__ Ww1, const float* __restrict__ Ww2,
    const float* __restrict__ Wc1, const float* __restrict__ Wc2,
    const float* __restrict__ Wc3,
    _Float16* __restrict__ W1tG, _Float16* __restrict__ W2tG,
    _Float16* __restrict__ Wc1tG, _Float16* __restrict__ Wc2tG,
    _Float16* __restrict__ Wc3tG)
{
    extern __shared__ char smem[];
    const int t = threadIdx.x;
    const int lane = t & 63;
    const int wv = t >> 6;
    if (blockIdx.x < 1024) {
        unsigned* pk = (unsigned*)smem;
        const int q = blockIdx.x * 8 + wv;
#pragma unroll
        for (int i = 0; i < 16; i++) {
            int j = i * 512 + t;
            int4 c = idx4[j];
            pk[j] = (unsigned)c.y | ((unsigned)c.z << 8) |
                    ((unsigned)c.w << 16);
        }
        const int4 qc = idx4[q];
        const int qx = qc.y, qy = qc.z, qz = qc.w;
        const unsigned qq = (unsigned)(qx * qx + qy * qy + qz * qz);
#if __has_builtin(__builtin_amdgcn_udot4)
        const unsigned qpk2 = (unsigned)(2 * qx) | ((unsigned)(2 * qy) << 8) |
                              ((unsigned)(2 * qz) << 16);
#endif
        unsigned a0 = 0xFFFFFFFFu, a1 = 0xFFFFFFFFu, a2 = 0xFFFFFFFFu,
                 a3 = 0xFFFFFFFFu;
        unsigned b0 = 0xFFFFFFFFu, b1 = 0xFFFFFFFFu, b2 = 0xFFFFFFFFu,
                 b3 = 0xFFFFFFFFu;
        __syncthreads();
        const uint4* pk4 = (const uint4*)pk;
#pragma unroll 4
        for (int i = 0; i < 32; ++i) {
            uint4 cd = pk4[i * 64 + lane];
            const unsigned j0 = (unsigned)((i * 64 + lane) * 4);
#if __has_builtin(__builtin_amdgcn_udot4)
            unsigned d20 = __builtin_amdgcn_udot4(cd.x, cd.x, qq, false) -
                           __builtin_amdgcn_udot4(cd.x, qpk2, 0u, false);
            unsigned d21 = __builtin_amdgcn_udot4(cd.y, cd.y, qq, false) -
                           __builtin_amdgcn_udot4(cd.y, qpk2, 0u, false);
            unsigned d22 = __builtin_amdgcn_udot4(cd.z, cd.z, qq, false) -
                           __builtin_amdgcn_udot4(cd.z, qpk2, 0u, false);
            unsigned d23 = __builtin_amdgcn_udot4(cd.w, cd.w, qq, false) -
                           __builtin_amdgcn_udot4(cd.w, qpk2, 0u, false);
#else
            unsigned d20, d21, d22, d23;
            {
                unsigned ps[4] = {cd.x, cd.y, cd.z, cd.w};
                unsigned ds[4];
#pragma unroll
                for (int c = 0; c < 4; c++) {
                    int x = (int)(ps[c] & 255u), y = (int)((ps[c] >> 8) & 255u),
                        z = (int)(ps[c] >> 16);
                    int dx = x - qx, dy = y - qy, dz = z - qz;
                    ds[c] = (unsigned)(dx * dx + dy * dy + dz * dz);
                }
                d20 = ds[0]; d21 = ds[1]; d22 = ds[2]; d23 = ds[3];
            }
#endif
            insert4(a0, a1, a2, a3, (d20 << 13) + j0);
            insert4(a0, a1, a2, a3, (d21 << 13) + j0 + 1);
            insert4(b0, b1, b2, b3, (d22 << 13) + j0 + 2);
            insert4(b0, b1, b2, b3, (d23 << 13) + j0 + 3);
        }
        unsigned t0 = min(a0, b3), t1 = min(a1, b2), t2 = min(a2, b1),
                 t3 = min(a3, b0);
        sort2(t0, t2); sort2(t1, t3); sort2(t0, t1); sort2(t2, t3);
        sort2(t1, t2);
        unsigned prefix = 0u;
#pragma unroll
        for (int bit = 28; bit >= 0; --bit) {
            unsigned cand = prefix | (1u << bit);
            int c = __popcll(__ballot(t0 < cand)) +
                    __popcll(__ballot(t1 < cand)) +
                    __popcll(__ballot(t2 < cand)) +
                    __popcll(__ballot(t3 < cand));
            if (c < 16) prefix = cand;
        }
        const unsigned T = prefix;
        {
            unsigned long long m0 = __ballot(t0 <= T);
            unsigned long long m1 = __ballot(t1 <= T);
            unsigned long long m2 = __ballot(t2 <= T);
            unsigned long long m3 = __ballot(t3 <= T);
            int base1 = __popcll(m0);
            int base2 = base1 + __popcll(m1);
            int base3 = base2 + __popcll(m2);
            int* dst = knn_out + q * 16;
            if (t0 <= T) dst[mbcnt64(m0)] = (int)(t0 & 8191u);
            if (t1 <= T) dst[base1 + mbcnt64(m1)] = (int)(t1 & 8191u);
            if (t2 <= T) dst[base2 + mbcnt64(m2)] = (int)(t2 & 8191u);
            if (t3 <= T) dst[base3 + mbcnt64(m3)] = (int)(t3 & 8191u);
        }
        unsigned long long bad = __ballot(t3 < T);
        if (bad) {
            unsigned c0 = 0xFFFFFFFFu, c1 = 0xFFFFFFFFu, c2 = 0xFFFFFFFFu,
                     c3 = 0xFFFFFFFFu, c4 = 0xFFFFFFFFu, c5 = 0xFFFFFFFFu,
                     c6 = 0xFFFFFFFFu, c7 = 0xFFFFFFFFu, c8 = 0xFFFFFFFFu,
                     c9 = 0xFFFFFFFFu, c10 = 0xFFFFFFFFu, c11 = 0xFFFFFFFFu,
                     c12 = 0xFFFFFFFFu, c13 = 0xFFFFFFFFu, c14 = 0xFFFFFFFFu,
                     c15 = 0xFFFFFFFFu;
            for (int i = 0; i < 128; ++i) {
                int j = i * 64 + lane;
                int4 cd = idx4[j];
                int dx = cd.y - qx, dy = cd.z - qy, dz = cd.w - qz;
                unsigned d2 = (unsigned)(dx * dx + dy * dy + dz * dz);
                unsigned key = (d2 << 13) + (unsigned)j;
                c15 = min(c15, key);
                sort2(c14, c15); sort2(c13, c14); sort2(c12, c13);
                sort2(c11, c12); sort2(c10, c11); sort2(c9, c10);
                sort2(c8, c9);   sort2(c7, c8);   sort2(c6, c7);
                sort2(c5, c6);   sort2(c4, c5);   sort2(c3, c4);
                sort2(c2, c3);   sort2(c1, c2);   sort2(c0, c1);
            }
            for (int r = 0; r < 16; ++r) {
                unsigned m = c0;
                m = min(m, (unsigned)__shfl_xor((int)m, 1, 64));
                m = min(m, (unsigned)__shfl_xor((int)m, 2, 64));
                m = min(m, (unsigned)__shfl_xor((int)m, 4, 64));
                m = min(m, (unsigned)__shfl_xor((int)m, 8, 64));
                m = min(m, (unsigned)__shfl_xor((int)m, 16, 64));
                m = min(m, (unsigned)__shfl_xor((int)m, 32, 64));
                if (lane == r) knn_out[q * 16 + r] = (int)(m & 8191u);
                bool win = (c0 == m);
                c0 = win ? c1 : c0;    c1 = win ? c2 : c1;
                c2 = win ? c3 : c2;    c3 = win ? c4 : c3;
                c4 = win ? c5 : c4;    c5 = win ? c6 : c5;
                c6 = win ? c7 : c6;    c7 = win ? c8 : c7;
                c8 = win ? c9 : c8;    c9 = win ? c10 : c9;
                c10 = win ? c11 : c10; c11 = win ? c12 : c11;
                c12 = win ? c13 : c12; c13 = win ? c14 : c13;
                c14 = win ? c15 : c14; c15 = win ? 0xFFFFFFFFu : c15;
            }
        }
    } else if (blockIdx.x < 1088) {
        _Float16* sBt = (_Float16*)smem;
        float* sbias = (float*)(smem + 192 * 72 * 2);
        const int col = lane & 15, g = lane >> 4;
        const int bid2 = blockIdx.x - 1024;
        const int row0w = bid2 * 128 + wv * 16;
        {
            const float* Ws[3] = {Wq, Wk, Wv};
#pragma unroll
            for (int m = 0; m < 3; m++) {
                int k = t >> 3, nb = (t & 7) * 8;
                const float4* src = (const float4*)(Ws[m] + k * 64 + nb);
                float4 w0 = src[0], w1 = src[1];
                _Float16* dst = &sBt[(m * 64 + nb) * 72 + k];
                dst[0 * 72] = (_Float16)w0.x; dst[1 * 72] = (_Float16)w0.y;
                dst[2 * 72] = (_Float16)w0.z; dst[3 * 72] = (_Float16)w0.w;
                dst[4 * 72] = (_Float16)w1.x; dst[5 * 72] = (_Float16)w1.y;
                dst[6 * 72] = (_Float16)w1.z; dst[7 * 72] = (_Float16)w1.w;
            }
            if (t < 64) sbias[t] = bq[t];
            else if (t < 128) sbias[t] = bk[t - 64];
            else if (t < 192) sbias[t] = bv[t - 128];
        }
        __syncthreads();
        f16x8 au[2];
#pragma unroll
        for (int kc = 0; kc < 2; kc++) {
            const float4* src = (const float4*)
                (feats + (row0w + col) * 64 + kc * 32 + g * 8);
            float4 v0 = src[0], v1 = src[1];
            au[kc][0] = (_Float16)v0.x; au[kc][1] = (_Float16)v0.y;
            au[kc][2] = (_Float16)v0.z; au[kc][3] = (_Float16)v0.w;
            au[kc][4] = (_Float16)v1.x; au[kc][5] = (_Float16)v1.y;
            au[kc][6] = (_Float16)v1.z; au[kc][7] = (_Float16)v1.w;
        }
        float* outs[3] = {xq, xk, xv};
#pragma unroll
        for (int f = 0; f < 12; f++) {
            f32x4 acc;
            float bias = sbias[f * 16 + col];
#pragma unroll
            for (int r = 0; r < 4; r++) acc[r] = bias;
#pragma unroll
            for (int kc = 0; kc < 2; kc++) {
                f16x8 bw = *(const f16x8*)
                    &sBt[(f * 16 + col) * 72 + kc * 32 + g * 8];
                acc = __builtin_amdgcn_mfma_f32_16x16x32_f16(au[kc], bw, acc,
                                                             0, 0, 0);
            }
            float* o = outs[f >> 2];
            int cg = (f & 3) * 16 + col;
#pragma unroll
            for (int r = 0; r < 4; r++)
                o[(row0w + g * 4 + r) * 64 + cg] = acc[r];
        }
    } else {
        for (int o = t; o < 8192; o += 512) {
            int n = o >> 6, k = o & 63;
            W1tG[o] = (_Float16)Ww1[k * 128 + n];
        }
        for (int o = t; o < 8192; o += 512) {
            int n = o >> 7, k = o & 127;
            W2tG[o] = (_Float16)Ww2[k * 64 + n];
        }
        for (int o = t; o < 16384; o += 512) {
            int n = o >> 7, k = o & 127;
            Wc1tG[o] = (_Float16)Wc1[k * 128 + n];
        }
        for (int o = t; o < 16384; o += 512) {
            int n = o >> 7, k = o & 127;
            Wc2tG[o] = (_Float16)Wc2[k * 128 + n];
        }
        for (int o = t; o < 8192; o += 512) {
            int n = o >> 7, k = o & 127;
            Wc3tG[o] = (_Float16)Wc3[k * 64 + n];
        }
    }
}

// ---------------------------------------------------------------------------
// K2: MFMA vector-attention, LOW-LDS (~48KB -> 3 blocks/CU, 24 waves/CU vs
// 16). Per-wave scratch cut 16x136 -> 16x40 by K-chunking u (2 chunks) and
// o1 (4 chunks) through it — wave-private, no extra barriers. p_r uses
// mfma 16x16x16 (K=16=PH: half the A/B regs, no zero-pad). g2/b2 epilogue
// constants in LDS. Target VGPR <= 85 for 6 waves/SIMD (R9's spill came
// from capping a larger live set).
// ---------------------------------------------------------------------------
__global__ __launch_bounds__(512, 6) void attn_kernel(
    const int4* __restrict__ idx4, const int* __restrict__ knn,
    const float* __restrict__ xq, const float* __restrict__ xk,
    const float* __restrict__ xv,
    const float* __restrict__ Wp1, const float* __restrict__ pg,
    const float* __restrict__ pb, const float* __restrict__ Wp2,
    const float* __restrict__ bp2,
    const float* __restrict__ wg1, const float* __restrict__ wb1,
    const _Float16* __restrict__ W1tG,
    const float* __restrict__ wg2, const float* __restrict__ wb2,
    const _Float16* __restrict__ W2tG,
    float* __restrict__ attn)
{
    __shared__ _Float16 sW1t[128 * 72];    // 18.0 KB
    __shared__ _Float16 sW2t[64 * 136];    // 17.0 KB
    __shared__ _Float16 sscr[8][16 * 40];  // 10.0 KB (per-wave 16x40)
    __shared__ float sWp1[48], sPg[16], sPb[16];
    __shared__ float sg2[128], sb2[128];

    const int t = threadIdx.x;
    const int lane = t & 63;
    const int wv = t >> 6;
    const int col = lane & 15, g = lane >> 4;
    const int q = blockIdx.x * 8 + wv;

    const int jA = knn[q * 16 + col];
    const int4 jC = *(const int4*)(knn + q * 16 + g * 4);
    const int jr[4] = {jC.x, jC.y, jC.z, jC.w};
    const int4 pc = idx4[jA];
    const int4 qc = idx4[q];
    float xqv[4], xkv[4][4], xvv[4][4];
#pragma unroll
    for (int f = 0; f < 4; f++) xqv[f] = xq[q * 64 + f * 16 + col];
#pragma unroll
    for (int r = 0; r < 4; r++)
#pragma unroll
        for (int f = 0; f < 4; f++) {
            xkv[r][f] = xk[jr[r] * 64 + f * 16 + col];
            xvv[r][f] = xv[jr[r] * 64 + f * 16 + col];
        }

    for (int i = t; i < 1024; i += 512) {
        int n = i >> 3, ko = i & 7;
        *(f16x8*)&sW1t[n * 72 + ko * 8] =
            *(const f16x8*)&W1tG[n * 64 + ko * 8];
    }
    for (int i = t; i < 1024; i += 512) {
        int m = i >> 4, ko = i & 15;
        *(f16x8*)&sW2t[m * 136 + ko * 8] =
            *(const f16x8*)&W2tG[m * 128 + ko * 8];
    }
    if (t < 48) sWp1[t] = Wp1[t];
    if (t < 16) { sPg[t] = pg[t] * BN_INV; sPb[t] = pb[t]; }
    if (t >= 64 && t < 192) {
        int o = t - 64;
        sg2[o] = wg2[o] * BN_INV;
        sb2[o] = wb2[o];
    }

    float g1c[4], b1c[4], bp2c[4];
#pragma unroll
    for (int f = 0; f < 4; f++) {
        int c = f * 16 + col;
        g1c[f] = wg1[c] * BN_INV; b1c[f] = wb1[c];
        bp2c[f] = bp2[c];
    }
    __syncthreads();

    _Float16* scr = sscr[wv];

    // ---- p_r ----
    const float px = (float)(pc.y - qc.y);
    const float py = (float)(pc.z - qc.z);
    const float pz = (float)(pc.w - qc.w);
    f32x4 pr[4];
#if __has_builtin(__builtin_amdgcn_mfma_f32_16x16x16f16)
    {
        f16x4 aph;
#pragma unroll
        for (int j = 0; j < 4; j++) {
            int h = g * 4 + j;
            float v = px * sWp1[h] + py * sWp1[16 + h] + pz * sWp1[32 + h];
            v = fmaxf(v * sPg[h] + sPb[h], 0.f);
            aph[j] = (_Float16)v;
        }
#pragma unroll
        for (int f = 0; f < 4; f++) {
            f16x4 bP;
#pragma unroll
            for (int j = 0; j < 4; j++)
                bP[j] = (_Float16)Wp2[(g * 4 + j) * 64 + f * 16 + col];
            f32x4 cini;
#pragma unroll
            for (int r = 0; r < 4; r++) cini[r] = bp2c[f];
            pr[f] = __builtin_amdgcn_mfma_f32_16x16x16f16(aph, bP, cini,
                                                          0, 0, 0);
        }
    }
#else
    {
        f16x8 aph;
#pragma unroll
        for (int j = 0; j < 8; j++) {
            int h = g * 8 + j;
            float v = 0.f;
            if (g < 2) {
                v = px * sWp1[h] + py * sWp1[16 + h] + pz * sWp1[32 + h];
                v = fmaxf(v * sPg[h] + sPb[h], 0.f);
            }
            aph[j] = (_Float16)v;
        }
#pragma unroll
        for (int f = 0; f < 4; f++) {
            f16x8 bP;
#pragma unroll
            for (int j = 0; j < 8; j++) {
                int h = g * 8 + j;
                bP[j] = (g < 2) ? (_Float16)Wp2[h * 64 + f * 16 + col]
                                : (_Float16)0.f;
            }
            f32x4 cini;
#pragma unroll
            for (int r = 0; r < 4; r++) cini[r] = bp2c[f];
            pr[f] = __builtin_amdgcn_mfma_f32_16x16x32_f16(aph, bP, cini,
                                                           0, 0, 0);
        }
    }
#endif
    // ---- GEMM1, K-chunked through 16x40 scr; vvr built alongside ----
    f32x4 vvr[4];
    f32x4 acc1[8];
#pragma unroll
    for (int f = 0; f < 8; f++)
#pragma unroll
        for (int r = 0; r < 4; r++) acc1[f][r] = 0.f;
#pragma unroll
    for (int kc = 0; kc < 2; kc++) {
#pragma unroll
        for (int fp = 0; fp < 2; fp++) {
            int f = kc * 2 + fp;
#pragma unroll
            for (int r = 0; r < 4; r++) {
                float w0 = xkv[r][f] - xqv[f] + pr[f][r];
                float uu = fmaxf(w0 * g1c[f] + b1c[f], 0.f);
                scr[(g * 4 + r) * 40 + fp * 16 + col] = (_Float16)uu;
                vvr[f][r] = xvv[r][f] + pr[f][r];
            }
        }
        f16x8 au = *(const f16x8*)&scr[col * 40 + g * 8];
#pragma unroll
        for (int f = 0; f < 8; f++) {
            f16x8 bw = *(const f16x8*)
                &sW1t[(f * 16 + col) * 72 + kc * 32 + g * 8];
            acc1[f] = __builtin_amdgcn_mfma_f32_16x16x32_f16(au, bw, acc1[f],
                                                             0, 0, 0);
        }
    }
    // ---- o1 epilogue to f16 regs (frees acc1) ----
    _Float16 o1v[8][4];
#pragma unroll
    for (int f = 0; f < 8; f++) {
        float gn = sg2[f * 16 + col], bs = sb2[f * 16 + col];
#pragma unroll
        for (int r = 0; r < 4; r++)
            o1v[f][r] = (_Float16)fmaxf(acc1[f][r] * gn + bs, 0.f);
    }
    // ---- GEMM2, K-chunked (bw2 dropped: cancels in softmax over s) ----
    f32x4 accL[4];
#pragma unroll
    for (int f = 0; f < 4; f++)
#pragma unroll
        for (int r = 0; r < 4; r++) accL[f][r] = 0.f;
#pragma unroll
    for (int c = 0; c < 4; c++) {
#pragma unroll
        for (int fp = 0; fp < 2; fp++)
#pragma unroll
            for (int r = 0; r < 4; r++)
                scr[(g * 4 + r) * 40 + fp * 16 + col] = o1v[c * 2 + fp][r];
        f16x8 ao = *(const f16x8*)&scr[col * 40 + g * 8];
#pragma unroll
        for (int f = 0; f < 4; f++) {
            f16x8 bw = *(const f16x8*)
                &sW2t[(f * 16 + col) * 136 + c * 32 + g * 8];
            accL[f] = __builtin_amdgcn_mfma_f32_16x16x32_f16(ao, bw, accL[f],
                                                             0, 0, 0);
        }
    }
    // ---- softmax over s + einsum ----
    float outv[4];
#pragma unroll
    for (int f = 0; f < 4; f++) {
        float mx = fmaxf(fmaxf(accL[f][0], accL[f][1]),
                         fmaxf(accL[f][2], accL[f][3]));
        mx = fmaxf(mx, __shfl_xor(mx, 16, 64));
        mx = fmaxf(mx, __shfl_xor(mx, 32, 64));
        float sum = 0.f, part = 0.f;
#pragma unroll
        for (int r = 0; r < 4; r++) {
            float e = __expf(accL[f][r] - mx);
            sum += e;
            part = fmaf(e, vvr[f][r], part);
        }
        sum += __shfl_xor(sum, 16, 64);
        sum += __shfl_xor(sum, 32, 64);
        part += __shfl_xor(part, 16, 64);
        part += __shfl_xor(part, 32, 64);
        outv[f] = part / sum;
    }
    float val = (g == 0) ? outv[0]
              : (g == 1) ? outv[1]
              : (g == 2) ? outv[2] : outv[3];
    attn[q * 64 + lane] = val;
}

// ---------------------------------------------------------------------------
// K3: FUSED MFMA-f16 head — now 512 blocks x 16 rows (R12 was 256 x 32):
// 2 blocks/CU overlap the 6-barrier weight-restage chain.
// ---------------------------------------------------------------------------
__global__ __launch_bounds__(256) void head_kernel(
    const float* __restrict__ feats, const float* __restrict__ attn,
    const _Float16* __restrict__ Wc1tG, const float* __restrict__ cg1,
    const float* __restrict__ cb1, const _Float16* __restrict__ Wc2tG,
    const float* __restrict__ cg2, const float* __restrict__ cb2,
    const _Float16* __restrict__ Wc3tG, const float* __restrict__ bc3,
    const float* __restrict__ lng, const float* __restrict__ lnb,
    float* __restrict__ out)
{
    __shared__ _Float16 sWt[128 * 136];
    __shared__ _Float16 sX[16 * 136];
    __shared__ _Float16 sY[16 * 136];
    __shared__ float sOut[16 * 68];
    __shared__ float sga[128], sba[128], sgb[128], sbb[128];
    __shared__ float sbc3[64], slng[64], slnb[64];

    const int t = threadIdx.x;
    const int lane = t & 63;
    const int wv = t >> 6;  // 0..3
    const int col = lane & 15, g = lane >> 4;
    const int row0 = blockIdx.x * 16;

    {
        int r = t >> 4, c0 = (t & 15) * 8;
        const float* src = (c0 < 64) ? (feats + (row0 + r) * 64 + c0)
                                     : (attn + (row0 + r) * 64 + (c0 - 64));
        float4 v0 = ((const float4*)src)[0];
        float4 v1 = ((const float4*)src)[1];
        _Float16* dst = &sX[r * 136 + c0];
        dst[0] = (_Float16)v0.x; dst[1] = (_Float16)v0.y;
        dst[2] = (_Float16)v0.z; dst[3] = (_Float16)v0.w;
        dst[4] = (_Float16)v1.x; dst[5] = (_Float16)v1.y;
        dst[6] = (_Float16)v1.z; dst[7] = (_Float16)v1.w;
    }
    auto stageWT = [&](const _Float16* WT, int chunks) {
        for (int i = t; i < chunks; i += 256) {
            int n = i >> 4, ko = i & 15;
            *(f16x8*)&sWt[n * 136 + ko * 8] =
                *(const f16x8*)&WT[n * 128 + ko * 8];
        }
    };
    stageWT(Wc1tG, 2048);
    if (t < 128) {
        sga[t] = cg1[t] * BN_INV; sba[t] = cb1[t];
        sgb[t] = cg2[t] * BN_INV; sbb[t] = cb2[t];
    } else if (t < 192) {
        int o = t - 128;
        sbc3[o] = bc3[o]; slng[o] = lng[o]; slnb[o] = lnb[o];
    }
    __syncthreads();
    // L1: 16x128 = 8 col-tiles; wave wv covers cols wv*32..wv*32+31
    {
        f16x8 ax[4];
#pragma unroll
        for (int kc = 0; kc < 4; kc++)
            ax[kc] = *(const f16x8*)&sX[col * 136 + kc * 32 + g * 8];
#pragma unroll
        for (int ft = 0; ft < 2; ft++) {
            int n = wv * 32 + ft * 16 + col;
            f32x4 acc;
#pragma unroll
            for (int r = 0; r < 4; r++) acc[r] = 0.f;
#pragma unroll
            for (int kc = 0; kc < 4; kc++) {
                f16x8 bw = *(const f16x8*)&sWt[n * 136 + kc * 32 + g * 8];
                acc = __builtin_amdgcn_mfma_f32_16x16x32_f16(ax[kc], bw, acc,
                                                             0, 0, 0);
            }
            float gn = sga[n], bs = sba[n];
#pragma unroll
            for (int r = 0; r < 4; r++)
                sY[(g * 4 + r) * 136 + n] =
                    (_Float16)fmaxf(acc[r] * gn + bs, 0.f);
        }
    }
    __syncthreads();
    stageWT(Wc2tG, 2048);
    __syncthreads();
    // L2: sY -> sX
    {
        f16x8 ax[4];
#pragma unroll
        for (int kc = 0; kc < 4; kc++)
            ax[kc] = *(const f16x8*)&sY[col * 136 + kc * 32 + g * 8];
#pragma unroll
        for (int ft = 0; ft < 2; ft++) {
            int n = wv * 32 + ft * 16 + col;
            f32x4 acc;
#pragma unroll
            for (int r = 0; r < 4; r++) acc[r] = 0.f;
#pragma unroll
            for (int kc = 0; kc < 4; kc++) {
                f16x8 bw = *(const f16x8*)&sWt[n * 136 + kc * 32 + g * 8];
                acc = __builtin_amdgcn_mfma_f32_16x16x32_f16(ax[kc], bw, acc,
                                                             0, 0, 0);
            }
            float gn = sgb[n], bs = sbb[n];
#pragma unroll
            for (int r = 0; r < 4; r++)
                sX[(g * 4 + r) * 136 + n] =
                    (_Float16)fmaxf(acc[r] * gn + bs, 0.f);
        }
    }
    __syncthreads();
    stageWT(Wc3tG, 1024);
    __syncthreads();
    // L3: 16x64; wave wv covers cols wv*16..wv*16+15
    {
        f16x8 ax[4];
#pragma unroll
        for (int kc = 0; kc < 4; kc++)
            ax[kc] = *(const f16x8*)&sX[col * 136 + kc * 32 + g * 8];
        int n = wv * 16 + col;
        f32x4 acc;
        float bias = sbc3[n];
#pragma unroll
        for (int r = 0; r < 4; r++) acc[r] = bias;
#pragma unroll
        for (int kc = 0; kc < 4; kc++) {
            f16x8 bw = *(const f16x8*)&sWt[n * 136 + kc * 32 + g * 8];
            acc = __builtin_amdgcn_mfma_f32_16x16x32_f16(ax[kc], bw, acc,
                                                         0, 0, 0);
        }
#pragma unroll
        for (int r = 0; r < 4; r++)
            sOut[(g * 4 + r) * 68 + n] = acc[r];
    }
    __syncthreads();
    // LN epilogue: r = t>>4, 16 lanes per row, width-16 shuffle
    {
        int r = t >> 4, o0 = (t & 15) * 4;
        float v[4];
        float s1 = 0.f, s2 = 0.f;
#pragma unroll
        for (int k = 0; k < 4; k++) {
            v[k] = sOut[r * 68 + o0 + k];
            s1 += v[k];
            s2 = fmaf(v[k], v[k], s2);
        }
#pragma unroll
        for (int d = 1; d < 16; d <<= 1) {
            s1 += __shfl_xor(s1, d, 16);
            s2 += __shfl_xor(s2, d, 16);
        }
        float m = s1 * (1.f / 64.f);
        float var = s2 * (1.f / 64.f) - m * m;
        float inv = 1.f / sqrtf(var + LN_EPS);
        float* dst = out + (row0 + r) * 64;
#pragma unroll
        for (int k = 0; k < 4; k++) {
            int o = o0 + k;
            dst[o] = (v[k] - m) * inv * slng[o] + slnb[o];
        }
    }
}

// ---------------------------------------------------------------------------
extern "C" void kernel_launch(void* const* d_in, const int* in_sizes, int n_in,
                              void* d_out, int out_size, void* d_ws,
                              size_t ws_size, hipStream_t stream)
{
    const int* indices = (const int*)d_in[0];
    const float* feats = (const float*)d_in[1];
    const float* Wq = (const float*)d_in[2];
    const float* bq = (const float*)d_in[3];
    const float* Wk = (const float*)d_in[4];
    const float* bk = (const float*)d_in[5];
    const float* Wv = (const float*)d_in[6];
    const float* bv = (const float*)d_in[7];
    const float* Wp1 = (const float*)d_in[8];
    const float* pg = (const float*)d_in[9];
    const float* pb = (const float*)d_in[10];
    const float* Wp2 = (const float*)d_in[11];
    const float* bp2 = (const float*)d_in[12];
    const float* wg1 = (const float*)d_in[13];
    const float* wb1 = (const float*)d_in[14];
    const float* Ww1 = (const float*)d_in[15];
    const float* wg2 = (const float*)d_in[16];
    const float* wb2 = (const float*)d_in[17];
    const float* Ww2 = (const float*)d_in[18];
    const float* Wc1 = (const float*)d_in[20];
    const float* cg1 = (const float*)d_in[21];
    const float* cb1 = (const float*)d_in[22];
    const float* Wc2 = (const float*)d_in[23];
    const float* cg2 = (const float*)d_in[24];
    const float* cb2 = (const float*)d_in[25];
    const float* Wc3 = (const float*)d_in[26];
    const float* bc3 = (const float*)d_in[27];
    const float* lng = (const float*)d_in[28];
    const float* lnb = (const float*)d_in[29];

    float* out = (float*)d_out;
    float* ws = (float*)d_ws;
    float* xq = ws;
    float* xk = xq + N * C;
    float* xv = xk + N * C;
    float* attn = xv + N * C;
    int* knn = (int*)(attn + N * C);
    _Float16* wt16 = (_Float16*)(knn + N * 16);
    _Float16* W1tG = wt16;              // 128 x 64
    _Float16* W2tG = W1tG + 8192;       // 64 x 128
    _Float16* Wc1tG = W2tG + 8192;      // 128 x 128
    _Float16* Wc2tG = Wc1tG + 16384;    // 128 x 128
    _Float16* Wc3tG = Wc2tG + 16384;    // 64 x 128

    qkv_knn_kernel<<<1089, 512, 32768, stream>>>(
        (const int4*)indices, knn, feats, Wq, bq, Wk, bk, Wv, bv, xq, xk, xv,
        Ww1, Ww2, Wc1, Wc2, Wc3, W1tG, W2tG, Wc1tG, Wc2tG, Wc3tG);
    attn_kernel<<<1024, 512, 0, stream>>>(
        (const int4*)indices, knn, xq, xk, xv, Wp1, pg, pb, Wp2, bp2, wg1,
        wb1, W1tG, wg2, wb2, W2tG, attn);
    head_kernel<<<512, 256, 0, stream>>>(feats, attn, Wc1tG, cg1, cb1, Wc2tG,
                                         cg2, cb2, Wc3tG, bc3, lng, lnb, out);
}